// Round 6
// baseline (337.817 us; speedup 1.0000x reference)
//
#include <hip/hip_runtime.h>
#include <hip/hip_bf16.h>

typedef __hip_bfloat16 bf16;
typedef __attribute__((ext_vector_type(8))) short short8;
typedef __attribute__((ext_vector_type(4))) short short4v;
typedef __attribute__((ext_vector_type(4))) float float4v;
typedef __attribute__((ext_vector_type(2))) float float2v;

__device__ __forceinline__ short f2bs(float f){
    union { bf16 h; short s; } u; u.h = __float2bfloat16(f); return u.s;
}
__device__ __forceinline__ float bs2f(short s){
    return __uint_as_float(((unsigned)(unsigned short)s) << 16);
}
__device__ __forceinline__ float gelu_exact(float x){
    return 0.5f * x * (1.0f + erff(x * 0.70710678118654752440f));
}
#define MFMA(a,b,c) __builtin_amdgcn_mfma_f32_16x16x32_bf16((a),(b),(c),0,0,0)

#define HW 16384
#define NPLANE 1048576
#define EPS 1e-5f
// XOR-swizzled index into a 64x64 bf16 tile (8-short chunks, m214 G4 pattern):
// kills the 8-way bank aliasing of the old 144B-row layout.
#define SWI(t,c) ((((t)<<6)) | (((((c)>>3) ^ ((t)&7)) & 7) << 3) | ((c)&7))

// wb layout (shorts): 0:w1b 4096:w2b 8192:qwb 12288:kvwb(8192) 20480:pwb 24576:fw1b 28672:fw2b
#define OFF_W1   0
#define OFF_W2   4096
#define OFF_QW   8192
#define OFF_KVW  12288
#define OFF_PW   20480
#define OFF_FW1  24576
#define OFF_FW2  28672

// ---------------- Kernel 1: LN1 stats (blocks 0..1023) + weight prep (1024..1032) ----------------
__global__ __launch_bounds__(256) void k_pre(const float* __restrict__ x,
                                             float* __restrict__ mu,
                                             float* __restrict__ rinv,
                                             const float* __restrict__ w1, const float* __restrict__ w2,
                                             const float* __restrict__ qw, const float* __restrict__ kvw,
                                             const float* __restrict__ pw, const float* __restrict__ fw1,
                                             const float* __restrict__ fw2,
                                             short* __restrict__ wb, float* __restrict__ rowsum){
    int bi = blockIdx.x;
    int tid = threadIdx.x;
    if (bi < 1024){
        const float* p = x + (size_t)bi * HW;
        float s = 0.f, ss = 0.f;
        for (int i = tid; i < HW/4; i += 256){
            float4v v = *(const float4v*)(p + i*4);
            #pragma unroll
            for (int k = 0; k < 4; k++){ s += v[k]; ss += v[k]*v[k]; }
        }
        __shared__ float rs[256], rss[256];
        rs[tid] = s; rss[tid] = ss; __syncthreads();
        for (int st = 128; st > 0; st >>= 1){
            if (tid < st){ rs[tid] += rs[tid+st]; rss[tid] += rss[tid+st]; }
            __syncthreads();
        }
        if (tid == 0){
            float m = rs[0] * (1.f/HW);
            float v = rss[0] * (1.f/HW) - m*m;
            mu[bi] = m; rinv[bi] = rsqrtf(v + EPS);
        }
    } else if (bi < 1032){
        int wi = bi - 1024;
        const float* src = wi==0?w1: wi==1?w2: wi==2?qw: wi==3?kvw: wi==4?(kvw+4096): wi==5?pw: wi==6?fw1: fw2;
        short* dst = wb + wi*4096;
        int base = tid*16;
        short8 o8[2];
        #pragma unroll
        for (int k = 0; k < 2; k++){
            float4v v0 = *(const float4v*)(src + base + 8*k);
            float4v v1 = *(const float4v*)(src + base + 8*k + 4);
            #pragma unroll
            for (int j = 0; j < 4; j++){ o8[k][j] = f2bs(v0[j]); o8[k][4+j] = f2bs(v1[j]); }
        }
        *(short8*)&dst[base]     = o8[0];
        *(short8*)&dst[base + 8] = o8[1];
    } else {
        if (tid < 128){
            int br = tid >> 6, o = tid & 63;
            const float* W = br ? w2 : w1;
            float s = 0.f;
            for (int c = 0; c < 64; c++) s += W[o*64 + c];
            rowsum[br*64 + o] = s;
        }
    }
}

// ---------------- Kernel 2: LN1 + 1x1 conv stats, 2 tiles per block ----------------
// 2048 blocks = 16 b x 128 chunks; swizzled staging tile; register accumulation;
// ONE shuffle-reduce + partial store per block.
__global__ __launch_bounds__(256, 4) void k_conv(const float* __restrict__ x,
                                              const float* __restrict__ mu,
                                              const float* __restrict__ rinv,
                                              const float* __restrict__ g1a, const float* __restrict__ b1a,
                                              const float* __restrict__ cb1,
                                              const float* __restrict__ g1b, const float* __restrict__ b1b,
                                              const float* __restrict__ cb2,
                                              const short* __restrict__ wb,
                                              const float* __restrict__ rowsum,
                                              float* __restrict__ partS, float* __restrict__ partQ){
    int blk = blockIdx.x;
    int b = blk >> 7; int chunk = blk & 127;
    __shared__ __align__(16) short xn_bf[64*64];
    const int tid = threadIdx.x;
    const int wq = tid >> 6, lane = tid & 63, qd = lane >> 4, col = lane & 15;
    const float4v zf = {0.f,0.f,0.f,0.f};
    const int p = tid & 63, cq = tid >> 6;

    float4v m4[4], r4[4];
    #pragma unroll
    for (int k = 0; k < 4; k++){
        m4[k] = *(const float4v*)(mu   + b*64 + 16*cq + 4*k);
        r4[k] = *(const float4v*)(rinv + b*64 + 16*cq + 4*k);
    }
    short8 a10 = *(const short8*)&wb[OFF_W1 + (16*wq + col)*64 + 8*qd];
    short8 a11 = *(const short8*)&wb[OFF_W1 + (16*wq + col)*64 + 32 + 8*qd];
    short8 a20 = *(const short8*)&wb[OFF_W2 + (16*wq + col)*64 + 8*qd];
    short8 a21 = *(const short8*)&wb[OFF_W2 + (16*wq + col)*64 + 32 + 8*qd];
    float cb1v[4], rs1v[4], cb2v[4], rs2v[4];
    #pragma unroll
    for (int r = 0; r < 4; r++){
        int o = 16*wq + 4*qd + r;
        cb1v[r] = cb1[o]; rs1v[r] = rowsum[o];
        cb2v[r] = cb2[o]; rs2v[r] = rowsum[64 + o];
    }
    float sa[2][4]  = {{0.f,0.f,0.f,0.f},{0.f,0.f,0.f,0.f}};
    float ssa[2][4] = {{0.f,0.f,0.f,0.f},{0.f,0.f,0.f,0.f}};

    for (int tl = 0; tl < 2; tl++){
        int hw0 = chunk*128 + tl*64;
        {
            const float* xb = x + (size_t)(b*64 + 16*cq)*HW + hw0 + p;
            short8 o8[2];
            #pragma unroll
            for (int k = 0; k < 2; k++)
                #pragma unroll
                for (int j = 0; j < 8; j++){
                    int jj = 8*k + j;
                    float v = xb[(size_t)jj*HW];
                    o8[k][j] = f2bs((v - m4[jj>>2][jj&3]) * r4[jj>>2][jj&3]);
                }
            *(short8*)&xn_bf[SWI(p, 16*cq)]     = o8[0];
            *(short8*)&xn_bf[SWI(p, 16*cq + 8)] = o8[1];
        }
        __syncthreads();
        #pragma unroll
        for (int jn = 0; jn < 4; jn++){
            short8 bx0 = *(const short8*)&xn_bf[SWI(16*jn + col, 8*qd)];
            short8 bx1 = *(const short8*)&xn_bf[SWI(16*jn + col, 32 + 8*qd)];
            int hw = hw0 + 16*jn + col;
            {
                float4v acc = zf;
                acc = MFMA(a10, bx0, acc);
                acc = MFMA(a11, bx1, acc);
                float gl = g1a[hw], bl = b1a[hw];
                #pragma unroll
                for (int r = 0; r < 4; r++){
                    float v = gl*acc[r] + bl*rs1v[r] + cb1v[r];
                    sa[0][r] += v; ssa[0][r] += v*v;
                }
            }
            {
                float4v acc = zf;
                acc = MFMA(a20, bx0, acc);
                acc = MFMA(a21, bx1, acc);
                float gl = g1b[hw], bl = b1b[hw];
                #pragma unroll
                for (int r = 0; r < 4; r++){
                    float v = gl*acc[r] + bl*rs2v[r] + cb2v[r];
                    sa[1][r] += v; ssa[1][r] += v*v;
                }
            }
        }
        __syncthreads();
    }

    #pragma unroll
    for (int br = 0; br < 2; br++)
        #pragma unroll
        for (int r = 0; r < 4; r++){
            float s = sa[br][r], ss = ssa[br][r];
            s += __shfl_xor(s, 1); ss += __shfl_xor(ss, 1);
            s += __shfl_xor(s, 2); ss += __shfl_xor(ss, 2);
            s += __shfl_xor(s, 4); ss += __shfl_xor(ss, 4);
            s += __shfl_xor(s, 8); ss += __shfl_xor(ss, 8);
            if (col == 0){
                int o = 16*wq + 4*qd + r;
                size_t pi = ((size_t)(br*16 + b)*64 + o)*128 + chunk;
                partS[pi] = s; partQ[pi] = ss;
            }
        }
}

// ---------------- Kernel 3: reduce LN2 partials (2048 rows x 128 chunks), wave-per-row ----------------
__global__ __launch_bounds__(256) void k_fin(const float* __restrict__ partS,
                                             const float* __restrict__ partQ,
                                             float* __restrict__ mu2,
                                             float* __restrict__ rinv2){
    int row = blockIdx.x*4 + (threadIdx.x >> 6);   // 0..2047
    int lane = threadIdx.x & 63;
    float2v a = *(const float2v*)(partS + (size_t)row*128 + lane*2);
    float2v b = *(const float2v*)(partQ + (size_t)row*128 + lane*2);
    float s  = a[0]+a[1];
    float ss = b[0]+b[1];
    #pragma unroll
    for (int st = 1; st < 64; st <<= 1){
        s  += __shfl_xor(s,  st);
        ss += __shfl_xor(ss, st);
    }
    if (lane == 0){
        float m = s * (1.f/HW);
        float v = ss * (1.f/HW) - m*m;
        mu2[row] = m; rinv2[row] = rsqrtf(v + EPS);
    }
}

// ---------------- Kernel 4: full fused window pipeline (swizzled LDS) ----------------
__global__ __launch_bounds__(256, 4) void k_attn(const float* __restrict__ x, float* __restrict__ outp,
                                              const float* __restrict__ mu1, const float* __restrict__ rinv1,
                                              const float* __restrict__ rowsum,
                                              const float* __restrict__ cb1, const float* __restrict__ cb2,
                                              const float* __restrict__ g1a, const float* __restrict__ b1a,
                                              const float* __restrict__ g1b, const float* __restrict__ b1b,
                                              const float* __restrict__ mu2, const float* __restrict__ rinv2,
                                              const float* __restrict__ g2a, const float* __restrict__ b2a,
                                              const float* __restrict__ g2b, const float* __restrict__ b2b,
                                              const float* __restrict__ pos1, const float* __restrict__ pos2,
                                              const short* __restrict__ wb,
                                              const float* __restrict__ qb, const float* __restrict__ kvb,
                                              const float* __restrict__ rpb, const float* __restrict__ gammap,
                                              const float* __restrict__ pb,
                                              const float* __restrict__ n2g, const float* __restrict__ n2b,
                                              const float* __restrict__ fb1,
                                              const float* __restrict__ fb2){
    int B = blockIdx.x;
    int hy = (B & 7) | ((B >> 5) & 8);
    int wx = (((B >> 9) & 7) << 1) | ((B >> 3) & 1);
    int b  = (B >> 4) & 15;

    const short* qwb  = wb + OFF_QW;
    const short* kvwb = wb + OFF_KVW;
    const short* pwb  = wb + OFF_PW;
    const short* f1b  = wb + OFF_FW1;
    const short* f2b  = wb + OFF_FW2;

    __shared__ __align__(16) char smem[36864];
    short* bufA = (short*)smem;                    // X1w -> P (wave-private)     [0..8192)
    short* bufK = (short*)(smem + 8192);           // K -> Y -> XO               [8192..16384)
    short* bufV = (short*)(smem + 16384);          // xn -> V^T -> Y^T           [16384..24576)
    short* bufQ = (short*)(smem + 24576);          // X2w -> Q                   [24576..32768)
    float* rpb_lds = (float*)(smem + 32768);       // 3600 (dead after head loop)
    // post-head-loop aliases (rpb region + XOf tail):
    float* XOf  = (float*)(smem + 16384);          // 64x66 fp32 (16896 B) over bufV+bufQ+spill -> ends 33280
    float* energyS = (float*)(smem + 33280);       // 1024 (after XOf end; rpb dead)
    short* soft_bf = (short*)(smem + 35840);       // 1024 -> ends 36864
    short* tnb  = (short*)smem;                    // tn bf16 over bufA
    short* h1b  = (short*)(smem + 8192);           // h1 over bufK
    float* sumS = (float*)(smem + 33280);          // 1024 (energyS dead by then)
    float* sqS  = (float*)(smem + 34304);          // 1024
    float* muS  = (float*)(smem + 35328);          // 256
    float* rinvS= (float*)(smem + 35584);          // 256

    const int tid = threadIdx.x;
    const int wq = tid >> 6, lane = tid & 63, qd = lane >> 4, col = lane & 15;
    size_t base = (size_t)b * NPLANE;
    #define HWOF(t) ((hy*8 + ((t)>>3))*128 + wx*8 + ((t)&7))

    const float4v zf = {0.f,0.f,0.f,0.f};
    const short8 zero8 = {0,0,0,0,0,0,0,0};

    for (int i = tid; i < 900; i += 256) rpb_lds[i] = rpb[i];

    // ---- P0: load raw x window + LN1 -> xn (bufV slot); lane owns row t ----
    {
        int t = tid & 63, cq = tid >> 6;
        int hw = HWOF(t);
        const float* mup = mu1   + b*64 + 16*cq;
        const float* rvp = rinv1 + b*64 + 16*cq;
        float4v m4[4], r4[4];
        #pragma unroll
        for (int k = 0; k < 4; k++){
            m4[k] = *(const float4v*)(mup + 4*k);
            r4[k] = *(const float4v*)(rvp + 4*k);
        }
        short8 o8[2];
        #pragma unroll
        for (int k = 0; k < 2; k++)
            #pragma unroll
            for (int j = 0; j < 8; j++){
                int jj = 8*k + j;
                float v = x[base + (size_t)(16*cq + jj)*HW + hw];
                o8[k][j] = f2bs((v - m4[jj>>2][jj&3]) * r4[jj>>2][jj&3]);
            }
        *(short8*)&bufV[SWI(t, 16*cq)]     = o8[0];
        *(short8*)&bufV[SWI(t, 16*cq + 8)] = o8[1];
    }
    __syncthreads();

    // ---- P1: both convs from xn, fused LN1-affine + LN2 + GELU + pos epilogue ----
    {
        short8 a10 = *(const short8*)&wb[OFF_W1 + (16*wq + col)*64 + 8*qd];
        short8 a11 = *(const short8*)&wb[OFF_W1 + (16*wq + col)*64 + 32 + 8*qd];
        short8 a20 = *(const short8*)&wb[OFF_W2 + (16*wq + col)*64 + 8*qd];
        short8 a21 = *(const short8*)&wb[OFF_W2 + (16*wq + col)*64 + 32 + 8*qd];
        float cb1v[4], rs1v[4], m2a[4], rv2a[4];
        float cb2v[4], rs2v[4], m2b[4], rv2b[4];
        #pragma unroll
        for (int r = 0; r < 4; r++){
            int o = 16*wq + 4*qd + r;
            cb1v[r] = cb1[o]; rs1v[r] = rowsum[o];
            m2a[r] = mu2[b*64 + o]; rv2a[r] = rinv2[b*64 + o];
            cb2v[r] = cb2[o]; rs2v[r] = rowsum[64 + o];
            m2b[r] = mu2[1024 + b*64 + o]; rv2b[r] = rinv2[1024 + b*64 + o];
        }
        #pragma unroll
        for (int jn = 0; jn < 4; jn++){
            int t = 16*jn + col; int hw = HWOF(t);
            short8 bx0 = *(const short8*)&bufV[SWI(t, 8*qd)];
            short8 bx1 = *(const short8*)&bufV[SWI(t, 32 + 8*qd)];
            {
                float4v acc = zf;
                acc = MFMA(a10, bx0, acc);
                acc = MFMA(a11, bx1, acc);
                float gl = g1a[hw], bl = b1a[hw], gg = g2a[hw], bo = b2a[hw];
                float4v p4 = *(const float4v*)(pos1 + t*64 + 16*wq + 4*qd);
                short4v pk;
                #pragma unroll
                for (int r = 0; r < 4; r++){
                    float v = gl*acc[r] + bl*rs1v[r] + cb1v[r];
                    float z = (v - m2a[r]) * rv2a[r] * gg + bo;
                    pk[r] = f2bs(gelu_exact(z) + p4[r]);
                }
                *(short4v*)&bufA[SWI(t, 16*wq + 4*qd)] = pk;
            }
            {
                float4v acc = zf;
                acc = MFMA(a20, bx0, acc);
                acc = MFMA(a21, bx1, acc);
                float gl = g1b[hw], bl = b1b[hw], gg = g2b[hw], bo = b2b[hw];
                float4v p4 = *(const float4v*)(pos2 + t*64 + 16*wq + 4*qd);
                short4v pk;
                #pragma unroll
                for (int r = 0; r < 4; r++){
                    float v = gl*acc[r] + bl*rs2v[r] + cb2v[r];
                    float z = (v - m2b[r]) * rv2b[r] * gg + bo;
                    pk[r] = f2bs(gelu_exact(z) + p4[r]);
                }
                *(short4v*)&bufQ[SWI(t, 16*wq + 4*qd)] = pk;
            }
        }
    }
    __syncthreads();

    // ---- P2: V^T and K from X2w (bufQ); xn (bufV) dead -> V^T target ----
    {
        short8 ax0 = *(const short8*)&bufQ[SWI(16*wq + col, 8*qd)];
        short8 ax1 = *(const short8*)&bufQ[SWI(16*wq + col, 32 + 8*qd)];
        #pragma unroll
        for (int jn = 0; jn < 4; jn++){
            int c = 16*jn + col;
            short8 wv0 = *(const short8*)&kvwb[(64 + c)*64 + 8*qd];
            short8 wv1 = *(const short8*)&kvwb[(64 + c)*64 + 32 + 8*qd];
            float4v acc = zf;
            acc = MFMA(ax0, wv0, acc);
            acc = MFMA(ax1, wv1, acc);
            float bv = kvb[64 + c];
            short4v pk;
            #pragma unroll
            for (int r = 0; r < 4; r++) pk[r] = f2bs(acc[r] + bv);
            *(short4v*)&bufV[SWI(c, 16*wq + 4*qd)] = pk;
        }
        short8 a0 = *(const short8*)&kvwb[(16*wq + col)*64 + 8*qd];
        short8 a1 = *(const short8*)&kvwb[(16*wq + col)*64 + 32 + 8*qd];
        float kbr[4];
        #pragma unroll
        for (int r = 0; r < 4; r++) kbr[r] = kvb[16*wq + 4*qd + r];
        #pragma unroll
        for (int jn = 0; jn < 4; jn++){
            int t = 16*jn + col;
            short8 bx0 = *(const short8*)&bufQ[SWI(t, 8*qd)];
            short8 bx1 = *(const short8*)&bufQ[SWI(t, 32 + 8*qd)];
            float4v acc = zf;
            acc = MFMA(a0, bx0, acc);
            acc = MFMA(a1, bx1, acc);
            short4v pk;
            #pragma unroll
            for (int r = 0; r < 4; r++) pk[r] = f2bs(acc[r] + kbr[r]);
            *(short4v*)&bufK[SWI(t, 16*wq + 4*qd)] = pk;
        }
    }
    __syncthreads();

    // ---- P3: Q from X1w (bufA) -> bufQ (X2w dead); capture X1w residual ----
    {
        short8 a0 = *(const short8*)&qwb[(16*wq + col)*64 + 8*qd];
        short8 a1 = *(const short8*)&qwb[(16*wq + col)*64 + 32 + 8*qd];
        float qbr[4];
        #pragma unroll
        for (int r = 0; r < 4; r++) qbr[r] = qb[16*wq + 4*qd + r];
        #pragma unroll
        for (int jn = 0; jn < 4; jn++){
            int t = 16*jn + col;
            short8 bx0 = *(const short8*)&bufA[SWI(t, 8*qd)];
            short8 bx1 = *(const short8*)&bufA[SWI(t, 32 + 8*qd)];
            float4v acc = zf;
            acc = MFMA(a0, bx0, acc);
            acc = MFMA(a1, bx1, acc);
            short4v pk;
            #pragma unroll
            for (int r = 0; r < 4; r++) pk[r] = f2bs((acc[r] + qbr[r]) * 0.25f);
            *(short4v*)&bufQ[SWI(t, 16*wq + 4*qd)] = pk;
        }
    }
    short4v xreg[4];
    #pragma unroll
    for (int h = 0; h < 4; h++){
        short4v xr;
        #pragma unroll
        for (int r = 0; r < 4; r++)
            xr[r] = bufA[SWI(16*wq + 4*qd + r, 16*h + col)];
        xreg[h] = xr;
    }
    __syncthreads();

    int idx_t[4][4];
    {
        int t = 16*wq + col, ty = t >> 3, tx = t & 7;
        #pragma unroll
        for (int jn = 0; jn < 4; jn++)
            #pragma unroll
            for (int r = 0; r < 4; r++){
                int u = 16*jn + 4*qd + r;
                idx_t[jn][r] = (ty - (u>>3) + 7)*15 + (tx - (u&7) + 7);
            }
    }

    // ---- head loop: S^T -> thread-local softmax -> P (wave-private) -> PV -> Y/Y^T ----
    for (int h = 0; h < 4; h++){
        short8 bq = *(const short8*)&bufQ[SWI(16*wq + col, h*16 + (qd & 1)*8)];
        float pr[4][4];
        #pragma unroll
        for (int jn = 0; jn < 4; jn++){
            short8 ak = *(const short8*)&bufK[SWI(16*jn + col, h*16 + (qd & 1)*8)];
            if (qd >= 2) ak = zero8;
            float4v acc = MFMA(ak, bq, zf);
            #pragma unroll
            for (int r = 0; r < 4; r++)
                pr[jn][r] = acc[r] + rpb_lds[idx_t[jn][r]*4 + h];
        }
        float m = pr[0][0];
        #pragma unroll
        for (int jn = 0; jn < 4; jn++)
            #pragma unroll
            for (int r = 0; r < 4; r++) m = fmaxf(m, pr[jn][r]);
        m = fmaxf(m, __shfl_xor(m, 16));
        m = fmaxf(m, __shfl_xor(m, 32));
        float s = 0.f;
        #pragma unroll
        for (int jn = 0; jn < 4; jn++)
            #pragma unroll
            for (int r = 0; r < 4; r++){ pr[jn][r] = __expf(pr[jn][r] - m); s += pr[jn][r]; }
        s += __shfl_xor(s, 16);
        s += __shfl_xor(s, 32);
        float rc = 1.f / s;
        #pragma unroll
        for (int jn = 0; jn < 4; jn++){
            short4v pk;
            #pragma unroll
            for (int r = 0; r < 4; r++) pk[r] = f2bs(pr[jn][r] * rc);
            *(short4v*)&bufA[SWI(16*wq + col, 16*jn + 4*qd)] = pk;
        }
        short8 ap0 = *(const short8*)&bufA[SWI(16*wq + col, 8*qd)];
        short8 ap1 = *(const short8*)&bufA[SWI(16*wq + col, 32 + 8*qd)];
        short8 bv0 = *(const short8*)&bufV[SWI(h*16 + col, 8*qd)];
        short8 bv1 = *(const short8*)&bufV[SWI(h*16 + col, 32 + 8*qd)];
        float4v acc_o = zf;
        acc_o = MFMA(ap0, bv0, acc_o);
        acc_o = MFMA(ap1, bv1, acc_o);
        __syncthreads();          // all waves done reading V rows of this head
        short4v ot;
        #pragma unroll
        for (int r = 0; r < 4; r++) ot[r] = f2bs(acc_o[r]);
        *(short4v*)&bufV[SWI(h*16 + col, 16*wq + 4*qd)] = ot;   // Y^T
        #pragma unroll
        for (int r = 0; r < 4; r++)
            bufK[SWI(16*wq + 4*qd + r, h*16 + col)] = ot[r];    // Y
    }
    __syncthreads();

    // ---- energy = Y Y^T (16x16, K=256) ----
    {
        float4v acc_e = zf;
        #pragma unroll
        for (int h = 0; h < 4; h++){
            short8 f0 = *(const short8*)&bufV[SWI(h*16 + col, 8*qd)];
            short8 f1 = *(const short8*)&bufV[SWI(h*16 + col, 32 + 8*qd)];
            acc_e = MFMA(f0, f0, acc_e);
            acc_e = MFMA(f1, f1, acc_e);
        }
        if (wq == 0){
            #pragma unroll
            for (int r = 0; r < 4; r++) energyS[(4*qd + r)*16 + col] = acc_e[r];
        }
    }
    __syncthreads();
    if (tid < 16){
        int i = tid; float m = -1e30f;
        for (int j = 0; j < 16; j++) m = fmaxf(m, energyS[i*16 + j]);
        float s = 0.f; float e[16];
        for (int j = 0; j < 16; j++){ e[j] = __expf(energyS[i*16 + j] - m); s += e[j]; }
        float rc = 1.f / s;
        for (int j = 0; j < 16; j++) soft_bf[i*32 + j] = f2bs(e[j] * rc);
        for (int j = 0; j < 16; j++) soft_bf[i*32 + 16 + j] = 0;
    }
    __syncthreads();

    // ---- lam + assemble XO -> bufK (overwrite Y slots, wave-private rows) ----
    {
        float gam = gammap[0];
        short8 asf = *(const short8*)&soft_bf[col*32 + 8*qd];
        #pragma unroll
        for (int h = 0; h < 4; h++){
            short8 ay = *(const short8*)&bufK[SWI(16*wq + col, 16*h + (qd & 1)*8)];
            float4v acc = MFMA(ay, asf, zf);
            short4v xv = xreg[h];
            #pragma unroll
            for (int r = 0; r < 4; r++){
                int ro = SWI(16*wq + 4*qd + r, 16*h + col);
                float ot = bs2f(bufK[ro]);
                float qv = bs2f(bufQ[ro]);
                float xo = gam*acc[r] + ot + qv + bs2f(xv[r]);
                bufK[ro] = f2bs(xo);
            }
        }
    }
    __syncthreads();

    // ---- proj: C[c][t] -> XOf[t*66+c] packed f2 ----
    {
        short8 a0 = *(const short8*)&pwb[(16*wq + col)*64 + 8*qd];
        short8 a1 = *(const short8*)&pwb[(16*wq + col)*64 + 32 + 8*qd];
        float pbr[4];
        #pragma unroll
        for (int r = 0; r < 4; r++) pbr[r] = pb[16*wq + 4*qd + r];
        #pragma unroll
        for (int jn = 0; jn < 4; jn++){
            int t = 16*jn + col;
            short8 bx0 = *(const short8*)&bufK[SWI(t, 8*qd)];
            short8 bx1 = *(const short8*)&bufK[SWI(t, 32 + 8*qd)];
            float4v acc = zf;
            acc = MFMA(a0, bx0, acc);
            acc = MFMA(a1, bx1, acc);
            float2v w0 = {acc[0]+pbr[0], acc[1]+pbr[1]};
            float2v w1 = {acc[2]+pbr[2], acc[3]+pbr[3]};
            *(float2v*)&XOf[t*66 + 16*wq + 4*qd]     = w0;
            *(float2v*)&XOf[t*66 + 16*wq + 4*qd + 2] = w1;
        }
    }
    __syncthreads();

    // ================= fused channel-MLP =================
    {
        int p = tid & 63, qg = tid >> 6;
        float s = 0.f, ss = 0.f;
        #pragma unroll
        for (int j = 0; j < 8; j++){
            float2v v = *(const float2v*)&XOf[p*66 + qg*16 + 2*j];
            s += v[0]+v[1]; ss += v[0]*v[0] + v[1]*v[1];
        }
        sumS[qg*64 + p] = s; sqS[qg*64 + p] = ss;
    }
    __syncthreads();
    if (tid < 64){
        float s  = sumS[tid] + sumS[64+tid] + sumS[128+tid] + sumS[192+tid];
        float ss = sqS[tid]  + sqS[64+tid]  + sqS[128+tid]  + sqS[192+tid];
        float m = s * (1.f/64.f);
        float var = ss * (1.f/64.f) - m*m;
        muS[tid] = m; rinvS[tid] = rsqrtf(var + EPS);
    }
    __syncthreads();
    {
        int p = tid & 63, qg = tid >> 6;
        float m = muS[p], rv = rinvS[p];
        short8 o8[2];
        #pragma unroll
        for (int k = 0; k < 2; k++)
            #pragma unroll
            for (int j = 0; j < 8; j++){
                int c = qg*16 + k*8 + j;
                o8[k][j] = f2bs((XOf[p*66 + c] - m) * rv * n2g[c] + n2b[c]);
            }
        *(short8*)&tnb[SWI(p, qg*16)]     = o8[0];
        *(short8*)&tnb[SWI(p, qg*16 + 8)] = o8[1];
    }
    __syncthreads();
    // GEMM1: C[j][t]; h1b[t][j] packed
    {
        short8 a0 = *(const short8*)&f1b[(16*wq + col)*64 + 8*qd];
        short8 a1 = *(const short8*)&f1b[(16*wq + col)*64 + 32 + 8*qd];
        float fbr[4];
        #pragma unroll
        for (int r = 0; r < 4; r++) fbr[r] = fb1[16*wq + 4*qd + r];
        #pragma unroll
        for (int jn = 0; jn < 4; jn++){
            int t = 16*jn + col;
            short8 bx0 = *(const short8*)&tnb[SWI(t, 8*qd)];
            short8 bx1 = *(const short8*)&tnb[SWI(t, 32 + 8*qd)];
            float4v acc = zf;
            acc = MFMA(a0, bx0, acc);
            acc = MFMA(a1, bx1, acc);
            short4v pk;
            #pragma unroll
            for (int r = 0; r < 4; r++) pk[r] = f2bs(gelu_exact(acc[r] + fbr[r]));
            *(short4v*)&h1b[SWI(t, 16*wq + 4*qd)] = pk;
        }
    }
    __syncthreads();
    // GEMM2: out = xo + h1 @ W2^T + fb2 -> global planar fp32
    {
        short8 a0 = *(const short8*)&h1b[SWI(16*wq + col, 8*qd)];
        short8 a1 = *(const short8*)&h1b[SWI(16*wq + col, 32 + 8*qd)];
        #pragma unroll
        for (int jn = 0; jn < 4; jn++){
            int c2 = 16*jn + col;
            short8 f0 = *(const short8*)&f2b[c2*64 + 8*qd];
            short8 f1 = *(const short8*)&f2b[c2*64 + 32 + 8*qd];
            float4v acc = zf;
            acc = MFMA(a0, f0, acc);
            acc = MFMA(a1, f1, acc);
            float bv = fb2[c2];
            float4v ov;
            #pragma unroll
            for (int r = 0; r < 4; r++)
                ov[r] = acc[r] + bv + XOf[(16*wq + 4*qd + r)*66 + c2];
            int t0 = 16*wq + 4*qd;
            *(float4v*)(outp + base + (size_t)c2*HW + HWOF(t0)) = ov;
        }
    }
    #undef HWOF
}

extern "C" void kernel_launch(void* const* d_in, const int* in_sizes, int n_in,
                              void* d_out, int out_size, void* d_ws, size_t ws_size,
                              hipStream_t stream){
    const float* x        = (const float*)d_in[0];
    const float* l1_g1    = (const float*)d_in[1];
    const float* l1_b1    = (const float*)d_in[2];
    const float* l1_cw    = (const float*)d_in[3];
    const float* l1_cb    = (const float*)d_in[4];
    const float* l1_g2    = (const float*)d_in[5];
    const float* l1_b2    = (const float*)d_in[6];
    const float* l2_g1    = (const float*)d_in[7];
    const float* l2_b1    = (const float*)d_in[8];
    const float* l2_cw    = (const float*)d_in[9];
    const float* l2_cb    = (const float*)d_in[10];
    const float* l2_g2    = (const float*)d_in[11];
    const float* l2_b2    = (const float*)d_in[12];
    const float* pos1     = (const float*)d_in[13];
    const float* pos2     = (const float*)d_in[14];
    const float* q_w      = (const float*)d_in[15];
    const float* q_b      = (const float*)d_in[16];
    const float* kv_w     = (const float*)d_in[17];
    const float* kv_b     = (const float*)d_in[18];
    const float* rpb      = (const float*)d_in[19];
    const float* gamma    = (const float*)d_in[20];
    const float* proj_w   = (const float*)d_in[21];
    const float* proj_b   = (const float*)d_in[22];
    const float* norm2_g  = (const float*)d_in[23];
    const float* norm2_b  = (const float*)d_in[24];
    const float* fc1_w    = (const float*)d_in[25];
    const float* fc1_b    = (const float*)d_in[26];
    const float* fc2_w    = (const float*)d_in[27];
    const float* fc2_b    = (const float*)d_in[28];

    float* out = (float*)d_out;                 // final output only (written once)

    float* partS = (float*)d_ws;                // 2048*128 floats (1 MB)
    float* partQ = partS + (size_t)2048*128;    // 1 MB
    float* mu1   = partQ + (size_t)2048*128;    // 1024
    float* rinv1 = mu1 + 1024;                  // 1024
    float* mu2   = rinv1 + 1024;                // 2048
    float* rinv2 = mu2 + 2048;                  // 2048
    float* rowsumG = rinv2 + 2048;              // 128
    short* wbuf  = (short*)(rowsumG + 128);     // 32768 shorts

    k_pre  <<<1033, 256, 0, stream>>>(x, mu1, rinv1,
                                      l1_cw, l2_cw, q_w, kv_w, proj_w, fc1_w, fc2_w,
                                      wbuf, rowsumG);
    k_conv <<<2048, 256, 0, stream>>>(x, mu1, rinv1,
                                      l1_g1, l1_b1, l1_cb,
                                      l2_g1, l2_b1, l2_cb,
                                      wbuf, rowsumG,
                                      partS, partQ);
    k_fin  <<<512, 256, 0, stream>>>(partS, partQ, mu2, rinv2);
    k_attn <<<4096, 256, 0, stream>>>(x, out, mu1, rinv1, rowsumG,
                                      l1_cb, l2_cb,
                                      l1_g1, l1_b1, l2_g1, l2_b1,
                                      mu2, rinv2,
                                      l1_g2, l1_b2, l2_g2, l2_b2,
                                      pos1, pos2, wbuf, q_b, kv_b,
                                      rpb, gamma, proj_b,
                                      norm2_g, norm2_b, fc1_b, fc2_b);
}

// Round 7
// 334.100 us; speedup vs baseline: 1.0111x; 1.0111x over previous
//
#include <hip/hip_runtime.h>
#include <hip/hip_bf16.h>

typedef __hip_bfloat16 bf16;
typedef __attribute__((ext_vector_type(8))) short short8;
typedef __attribute__((ext_vector_type(4))) short short4v;
typedef __attribute__((ext_vector_type(4))) float float4v;
typedef __attribute__((ext_vector_type(2))) float float2v;

__device__ __forceinline__ short f2bs(float f){
    union { bf16 h; short s; } u; u.h = __float2bfloat16(f); return u.s;
}
__device__ __forceinline__ float bs2f(short s){
    return __uint_as_float(((unsigned)(unsigned short)s) << 16);
}
__device__ __forceinline__ float gelu_exact(float x){
    return 0.5f * x * (1.0f + erff(x * 0.70710678118654752440f));
}
#define MFMA(a,b,c) __builtin_amdgcn_mfma_f32_16x16x32_bf16((a),(b),(c),0,0,0)

#define HW 16384
#define NPLANE 1048576
#define EPS 1e-5f
#define LS 72             // LDS row stride in bf16 (144 B)

// wb layout (shorts): 0:w1b 4096:w2b 8192:qwb 12288:kvwb(8192) 20480:pwb 24576:fw1b 28672:fw2b
#define OFF_W1   0
#define OFF_W2   4096
#define OFF_QW   8192
#define OFF_KVW  12288
#define OFF_PW   20480
#define OFF_FW1  24576
#define OFF_FW2  28672

// ---------------- Kernel 1: LN1 stats (blocks 0..1023) + weight prep (1024..1032) ----------------
__global__ __launch_bounds__(256) void k_pre(const float* __restrict__ x,
                                             float* __restrict__ mu,
                                             float* __restrict__ rinv,
                                             const float* __restrict__ w1, const float* __restrict__ w2,
                                             const float* __restrict__ qw, const float* __restrict__ kvw,
                                             const float* __restrict__ pw, const float* __restrict__ fw1,
                                             const float* __restrict__ fw2,
                                             short* __restrict__ wb, float* __restrict__ rowsum){
    int bi = blockIdx.x;
    int tid = threadIdx.x;
    if (bi < 1024){
        const float* p = x + (size_t)bi * HW;
        float s = 0.f, ss = 0.f;
        for (int i = tid; i < HW/4; i += 256){
            float4v v = *(const float4v*)(p + i*4);
            #pragma unroll
            for (int k = 0; k < 4; k++){ s += v[k]; ss += v[k]*v[k]; }
        }
        __shared__ float rs[256], rss[256];
        rs[tid] = s; rss[tid] = ss; __syncthreads();
        for (int st = 128; st > 0; st >>= 1){
            if (tid < st){ rs[tid] += rs[tid+st]; rss[tid] += rss[tid+st]; }
            __syncthreads();
        }
        if (tid == 0){
            float m = rs[0] * (1.f/HW);
            float v = rss[0] * (1.f/HW) - m*m;
            mu[bi] = m; rinv[bi] = rsqrtf(v + EPS);
        }
    } else if (bi < 1032){
        int wi = bi - 1024;
        const float* src = wi==0?w1: wi==1?w2: wi==2?qw: wi==3?kvw: wi==4?(kvw+4096): wi==5?pw: wi==6?fw1: fw2;
        short* dst = wb + wi*4096;
        int base = tid*16;
        short8 o8[2];
        #pragma unroll
        for (int k = 0; k < 2; k++){
            float4v v0 = *(const float4v*)(src + base + 8*k);
            float4v v1 = *(const float4v*)(src + base + 8*k + 4);
            #pragma unroll
            for (int j = 0; j < 4; j++){ o8[k][j] = f2bs(v0[j]); o8[k][4+j] = f2bs(v1[j]); }
        }
        *(short8*)&dst[base]     = o8[0];
        *(short8*)&dst[base + 8] = o8[1];
    } else {
        if (tid < 128){
            int br = tid >> 6, o = tid & 63;
            const float* W = br ? w2 : w1;
            float s = 0.f;
            for (int c = 0; c < 64; c++) s += W[o*64 + c];
            rowsum[br*64 + o] = s;
        }
    }
}

// ---------------- Kernel 2: LN1 + 1x1 conv stats, 4 tiles per block (best measured) ----------------
__global__ __launch_bounds__(256, 4) void k_conv(const float* __restrict__ x,
                                              const float* __restrict__ mu,
                                              const float* __restrict__ rinv,
                                              const float* __restrict__ g1a, const float* __restrict__ b1a,
                                              const float* __restrict__ cb1,
                                              const float* __restrict__ g1b, const float* __restrict__ b1b,
                                              const float* __restrict__ cb2,
                                              const short* __restrict__ wb,
                                              const float* __restrict__ rowsum,
                                              float* __restrict__ partS, float* __restrict__ partQ){
    int blk = blockIdx.x;
    int b = blk >> 6; int chunk = blk & 63;
    __shared__ __align__(16) short xn_bf[64*LS];
    const int tid = threadIdx.x;
    const int wq = tid >> 6, lane = tid & 63, qd = lane >> 4, col = lane & 15;
    const float4v zf = {0.f,0.f,0.f,0.f};
    const int p = tid & 63, cq = tid >> 6;

    float4v m4[4], r4[4];
    #pragma unroll
    for (int k = 0; k < 4; k++){
        m4[k] = *(const float4v*)(mu   + b*64 + 16*cq + 4*k);
        r4[k] = *(const float4v*)(rinv + b*64 + 16*cq + 4*k);
    }
    short8 a10 = *(const short8*)&wb[OFF_W1 + (16*wq + col)*64 + 8*qd];
    short8 a11 = *(const short8*)&wb[OFF_W1 + (16*wq + col)*64 + 32 + 8*qd];
    short8 a20 = *(const short8*)&wb[OFF_W2 + (16*wq + col)*64 + 8*qd];
    short8 a21 = *(const short8*)&wb[OFF_W2 + (16*wq + col)*64 + 32 + 8*qd];
    float cb1v[4], rs1v[4], cb2v[4], rs2v[4];
    #pragma unroll
    for (int r = 0; r < 4; r++){
        int o = 16*wq + 4*qd + r;
        cb1v[r] = cb1[o]; rs1v[r] = rowsum[o];
        cb2v[r] = cb2[o]; rs2v[r] = rowsum[64 + o];
    }
    float sa[2][4]  = {{0.f,0.f,0.f,0.f},{0.f,0.f,0.f,0.f}};
    float ssa[2][4] = {{0.f,0.f,0.f,0.f},{0.f,0.f,0.f,0.f}};

    for (int tl = 0; tl < 4; tl++){
        int hw0 = chunk*256 + tl*64;
        {
            const float* xb = x + (size_t)(b*64 + 16*cq)*HW + hw0 + p;
            short8 o8[2];
            #pragma unroll
            for (int k = 0; k < 2; k++)
                #pragma unroll
                for (int j = 0; j < 8; j++){
                    int jj = 8*k + j;
                    float v = xb[(size_t)jj*HW];
                    o8[k][j] = f2bs((v - m4[jj>>2][jj&3]) * r4[jj>>2][jj&3]);
                }
            *(short8*)&xn_bf[p*LS + 16*cq]     = o8[0];
            *(short8*)&xn_bf[p*LS + 16*cq + 8] = o8[1];
        }
        __syncthreads();
        #pragma unroll
        for (int jn = 0; jn < 4; jn++){
            short8 bx0 = *(const short8*)&xn_bf[(16*jn + col)*LS + 8*qd];
            short8 bx1 = *(const short8*)&xn_bf[(16*jn + col)*LS + 32 + 8*qd];
            int hw = hw0 + 16*jn + col;
            {
                float4v acc = zf;
                acc = MFMA(a10, bx0, acc);
                acc = MFMA(a11, bx1, acc);
                float gl = g1a[hw], bl = b1a[hw];
                #pragma unroll
                for (int r = 0; r < 4; r++){
                    float v = gl*acc[r] + bl*rs1v[r] + cb1v[r];
                    sa[0][r] += v; ssa[0][r] += v*v;
                }
            }
            {
                float4v acc = zf;
                acc = MFMA(a20, bx0, acc);
                acc = MFMA(a21, bx1, acc);
                float gl = g1b[hw], bl = b1b[hw];
                #pragma unroll
                for (int r = 0; r < 4; r++){
                    float v = gl*acc[r] + bl*rs2v[r] + cb2v[r];
                    sa[1][r] += v; ssa[1][r] += v*v;
                }
            }
        }
        __syncthreads();
    }

    #pragma unroll
    for (int br = 0; br < 2; br++)
        #pragma unroll
        for (int r = 0; r < 4; r++){
            float s = sa[br][r], ss = ssa[br][r];
            s += __shfl_xor(s, 1); ss += __shfl_xor(ss, 1);
            s += __shfl_xor(s, 2); ss += __shfl_xor(ss, 2);
            s += __shfl_xor(s, 4); ss += __shfl_xor(ss, 4);
            s += __shfl_xor(s, 8); ss += __shfl_xor(ss, 8);
            if (col == 0){
                int o = 16*wq + 4*qd + r;
                size_t pi = ((size_t)(br*16 + b)*64 + o)*64 + chunk;
                partS[pi] = s; partQ[pi] = ss;
            }
        }
}

// ---------------- Kernel 3: reduce LN2 partials (2048 rows x 64 chunks), wave-per-row ----------------
__global__ __launch_bounds__(256) void k_fin(const float* __restrict__ partS,
                                             const float* __restrict__ partQ,
                                             float* __restrict__ mu2,
                                             float* __restrict__ rinv2){
    int row = blockIdx.x*4 + (threadIdx.x >> 6);   // 0..2047
    int lane = threadIdx.x & 63;
    float s  = partS[(size_t)row*64 + lane];
    float ss = partQ[(size_t)row*64 + lane];
    #pragma unroll
    for (int st = 1; st < 64; st <<= 1){
        s  += __shfl_xor(s,  st);
        ss += __shfl_xor(ss, st);
    }
    if (lane == 0){
        float m = s * (1.f/HW);
        float v = ss * (1.f/HW) - m*m;
        mu2[row] = m; rinv2[row] = rsqrtf(v + EPS);
    }
}

// ---------------- Kernel 4: full fused window pipeline (LS72, barrier-free head loop) ----------------
__global__ __launch_bounds__(256, 4) void k_attn(const float* __restrict__ x, float* __restrict__ outp,
                                              const float* __restrict__ mu1, const float* __restrict__ rinv1,
                                              const float* __restrict__ rowsum,
                                              const float* __restrict__ cb1, const float* __restrict__ cb2,
                                              const float* __restrict__ g1a, const float* __restrict__ b1a,
                                              const float* __restrict__ g1b, const float* __restrict__ b1b,
                                              const float* __restrict__ mu2, const float* __restrict__ rinv2,
                                              const float* __restrict__ g2a, const float* __restrict__ b2a,
                                              const float* __restrict__ g2b, const float* __restrict__ b2b,
                                              const float* __restrict__ pos1, const float* __restrict__ pos2,
                                              const short* __restrict__ wb,
                                              const float* __restrict__ qb, const float* __restrict__ kvb,
                                              const float* __restrict__ rpb, const float* __restrict__ gammap,
                                              const float* __restrict__ pb,
                                              const float* __restrict__ n2g, const float* __restrict__ n2b,
                                              const float* __restrict__ fb1,
                                              const float* __restrict__ fb2){
    int B = blockIdx.x;
    int hy = (B & 7) | ((B >> 5) & 8);
    int wx = (((B >> 9) & 7) << 1) | ((B >> 3) & 1);
    int b  = (B >> 4) & 15;

    const short* qwb  = wb + OFF_QW;
    const short* kvwb = wb + OFF_KVW;
    const short* pwb  = wb + OFF_PW;
    const short* f1b  = wb + OFF_FW1;
    const short* f2b  = wb + OFF_FW2;

    __shared__ __align__(16) char smem[40464];
    short* bufA = (short*)smem;                    // X1w -> P (wave-private)
    short* bufK = (short*)(smem + 9216);           // K -> Y[t][c] -> XO[t][c]
    short* bufV = (short*)(smem + 18432);          // xn -> V^T[c][t] -> Y^T[c][t]
    short* bufQ = (short*)(smem + 27648);          // X2w -> Q[t][c]
    float* rpb_lds = (float*)(smem + 36864);       // 3600 (dead after head loop)
    float* energyS = (float*)(smem + 36864);       // 1024, aliases rpb
    short* soft_bf = (short*)(smem + 37888);       // 1024, aliases rpb
    // tail aliases:
    float* XOf  = (float*)(smem + 18432);          // 64x66 fp32 (16896 B) over bufV+bufQ
    short* tnb  = (short*)smem;                    // tn bf16 over bufA
    short* h1b  = (short*)(smem + 9216);           // h1 over bufK
    float* sumS = (float*)(smem + 36864);          // 1024
    float* sqS  = (float*)(smem + 37888);          // 1024
    float* muS  = (float*)(smem + 38912);          // 256
    float* rinvS= (float*)(smem + 39168);          // 256

    const int tid = threadIdx.x;
    const int wq = tid >> 6, lane = tid & 63, qd = lane >> 4, col = lane & 15;
    size_t base = (size_t)b * NPLANE;
    #define HWOF(t) ((hy*8 + ((t)>>3))*128 + wx*8 + ((t)&7))

    const float4v zf = {0.f,0.f,0.f,0.f};
    const short8 zero8 = {0,0,0,0,0,0,0,0};

    for (int i = tid; i < 900; i += 256) rpb_lds[i] = rpb[i];

    // ---- P0: load raw x window + LN1 -> xn (bufV slot); lane owns row t ----
    {
        int t = tid & 63, cq = tid >> 6;
        int hw = HWOF(t);
        const float* mup = mu1   + b*64 + 16*cq;
        const float* rvp = rinv1 + b*64 + 16*cq;
        float4v m4[4], r4[4];
        #pragma unroll
        for (int k = 0; k < 4; k++){
            m4[k] = *(const float4v*)(mup + 4*k);
            r4[k] = *(const float4v*)(rvp + 4*k);
        }
        short8 o8[2];
        #pragma unroll
        for (int k = 0; k < 2; k++)
            #pragma unroll
            for (int j = 0; j < 8; j++){
                int jj = 8*k + j;
                float v = x[base + (size_t)(16*cq + jj)*HW + hw];
                o8[k][j] = f2bs((v - m4[jj>>2][jj&3]) * r4[jj>>2][jj&3]);
            }
        *(short8*)&bufV[t*LS + 16*cq]     = o8[0];
        *(short8*)&bufV[t*LS + 16*cq + 8] = o8[1];
    }
    __syncthreads();

    // ---- P1: both convs from xn, fused LN1-affine + LN2 + GELU + pos epilogue ----
    {
        short8 a10 = *(const short8*)&wb[OFF_W1 + (16*wq + col)*64 + 8*qd];
        short8 a11 = *(const short8*)&wb[OFF_W1 + (16*wq + col)*64 + 32 + 8*qd];
        short8 a20 = *(const short8*)&wb[OFF_W2 + (16*wq + col)*64 + 8*qd];
        short8 a21 = *(const short8*)&wb[OFF_W2 + (16*wq + col)*64 + 32 + 8*qd];
        float cb1v[4], rs1v[4], m2a[4], rv2a[4];
        float cb2v[4], rs2v[4], m2b[4], rv2b[4];
        #pragma unroll
        for (int r = 0; r < 4; r++){
            int o = 16*wq + 4*qd + r;
            cb1v[r] = cb1[o]; rs1v[r] = rowsum[o];
            m2a[r] = mu2[b*64 + o]; rv2a[r] = rinv2[b*64 + o];
            cb2v[r] = cb2[o]; rs2v[r] = rowsum[64 + o];
            m2b[r] = mu2[1024 + b*64 + o]; rv2b[r] = rinv2[1024 + b*64 + o];
        }
        #pragma unroll
        for (int jn = 0; jn < 4; jn++){
            int t = 16*jn + col; int hw = HWOF(t);
            short8 bx0 = *(const short8*)&bufV[t*LS + 8*qd];
            short8 bx1 = *(const short8*)&bufV[t*LS + 32 + 8*qd];
            {
                float4v acc = zf;
                acc = MFMA(a10, bx0, acc);
                acc = MFMA(a11, bx1, acc);
                float gl = g1a[hw], bl = b1a[hw], gg = g2a[hw], bo = b2a[hw];
                float4v p4 = *(const float4v*)(pos1 + t*64 + 16*wq + 4*qd);
                short4v pk;
                #pragma unroll
                for (int r = 0; r < 4; r++){
                    float v = gl*acc[r] + bl*rs1v[r] + cb1v[r];
                    float z = (v - m2a[r]) * rv2a[r] * gg + bo;
                    pk[r] = f2bs(gelu_exact(z) + p4[r]);
                }
                *(short4v*)&bufA[t*LS + 16*wq + 4*qd] = pk;
            }
            {
                float4v acc = zf;
                acc = MFMA(a20, bx0, acc);
                acc = MFMA(a21, bx1, acc);
                float gl = g1b[hw], bl = b1b[hw], gg = g2b[hw], bo = b2b[hw];
                float4v p4 = *(const float4v*)(pos2 + t*64 + 16*wq + 4*qd);
                short4v pk;
                #pragma unroll
                for (int r = 0; r < 4; r++){
                    float v = gl*acc[r] + bl*rs2v[r] + cb2v[r];
                    float z = (v - m2b[r]) * rv2b[r] * gg + bo;
                    pk[r] = f2bs(gelu_exact(z) + p4[r]);
                }
                *(short4v*)&bufQ[t*LS + 16*wq + 4*qd] = pk;
            }
        }
    }
    __syncthreads();

    // ---- P2: V^T and K from X2w (bufQ); xn (bufV) dead -> V^T target ----
    {
        short8 ax0 = *(const short8*)&bufQ[(16*wq + col)*LS + 8*qd];
        short8 ax1 = *(const short8*)&bufQ[(16*wq + col)*LS + 32 + 8*qd];
        #pragma unroll
        for (int jn = 0; jn < 4; jn++){
            int c = 16*jn + col;
            short8 wv0 = *(const short8*)&kvwb[(64 + c)*64 + 8*qd];
            short8 wv1 = *(const short8*)&kvwb[(64 + c)*64 + 32 + 8*qd];
            float4v acc = zf;
            acc = MFMA(ax0, wv0, acc);
            acc = MFMA(ax1, wv1, acc);
            float bv = kvb[64 + c];
            short4v pk;
            #pragma unroll
            for (int r = 0; r < 4; r++) pk[r] = f2bs(acc[r] + bv);
            *(short4v*)&bufV[c*LS + 16*wq + 4*qd] = pk;
        }
        short8 a0 = *(const short8*)&kvwb[(16*wq + col)*64 + 8*qd];
        short8 a1 = *(const short8*)&kvwb[(16*wq + col)*64 + 32 + 8*qd];
        float kbr[4];
        #pragma unroll
        for (int r = 0; r < 4; r++) kbr[r] = kvb[16*wq + 4*qd + r];
        #pragma unroll
        for (int jn = 0; jn < 4; jn++){
            int t = 16*jn + col;
            short8 bx0 = *(const short8*)&bufQ[t*LS + 8*qd];
            short8 bx1 = *(const short8*)&bufQ[t*LS + 32 + 8*qd];
            float4v acc = zf;
            acc = MFMA(a0, bx0, acc);
            acc = MFMA(a1, bx1, acc);
            short4v pk;
            #pragma unroll
            for (int r = 0; r < 4; r++) pk[r] = f2bs(acc[r] + kbr[r]);
            *(short4v*)&bufK[t*LS + 16*wq + 4*qd] = pk;
        }
    }
    __syncthreads();

    // ---- P3: Q from X1w (bufA) -> bufQ (X2w dead); capture X1w residual ----
    {
        short8 a0 = *(const short8*)&qwb[(16*wq + col)*64 + 8*qd];
        short8 a1 = *(const short8*)&qwb[(16*wq + col)*64 + 32 + 8*qd];
        float qbr[4];
        #pragma unroll
        for (int r = 0; r < 4; r++) qbr[r] = qb[16*wq + 4*qd + r];
        #pragma unroll
        for (int jn = 0; jn < 4; jn++){
            int t = 16*jn + col;
            short8 bx0 = *(const short8*)&bufA[t*LS + 8*qd];
            short8 bx1 = *(const short8*)&bufA[t*LS + 32 + 8*qd];
            float4v acc = zf;
            acc = MFMA(a0, bx0, acc);
            acc = MFMA(a1, bx1, acc);
            short4v pk;
            #pragma unroll
            for (int r = 0; r < 4; r++) pk[r] = f2bs((acc[r] + qbr[r]) * 0.25f);
            *(short4v*)&bufQ[t*LS + 16*wq + 4*qd] = pk;
        }
    }
    short4v xreg[4];
    #pragma unroll
    for (int h = 0; h < 4; h++){
        short4v xr;
        #pragma unroll
        for (int r = 0; r < 4; r++)
            xr[r] = bufA[(16*wq + 4*qd + r)*LS + 16*h + col];
        xreg[h] = xr;
    }
    __syncthreads();

    int idx_t[4][4];
    {
        int t = 16*wq + col, ty = t >> 3, tx = t & 7;
        #pragma unroll
        for (int jn = 0; jn < 4; jn++)
            #pragma unroll
            for (int r = 0; r < 4; r++){
                int u = 16*jn + 4*qd + r;
                idx_t[jn][r] = (ty - (u>>3) + 7)*15 + (tx - (u&7) + 7);
            }
    }

    // ---- head loop: BARRIER-FREE. S^T -> thread-local softmax -> P (wave-private) -> PV.
    //      Y kept in registers; committed to LDS after ONE barrier post-loop. ----
    short4v yreg[4];
    for (int h = 0; h < 4; h++){
        short8 bq = *(const short8*)&bufQ[(16*wq + col)*LS + h*16 + (qd & 1)*8];
        float pr[4][4];
        #pragma unroll
        for (int jn = 0; jn < 4; jn++){
            short8 ak = *(const short8*)&bufK[(16*jn + col)*LS + h*16 + (qd & 1)*8];
            if (qd >= 2) ak = zero8;
            float4v acc = MFMA(ak, bq, zf);
            #pragma unroll
            for (int r = 0; r < 4; r++)
                pr[jn][r] = acc[r] + rpb_lds[idx_t[jn][r]*4 + h];
        }
        float m = pr[0][0];
        #pragma unroll
        for (int jn = 0; jn < 4; jn++)
            #pragma unroll
            for (int r = 0; r < 4; r++) m = fmaxf(m, pr[jn][r]);
        m = fmaxf(m, __shfl_xor(m, 16));
        m = fmaxf(m, __shfl_xor(m, 32));
        float s = 0.f;
        #pragma unroll
        for (int jn = 0; jn < 4; jn++)
            #pragma unroll
            for (int r = 0; r < 4; r++){ pr[jn][r] = __expf(pr[jn][r] - m); s += pr[jn][r]; }
        s += __shfl_xor(s, 16);
        s += __shfl_xor(s, 32);
        float rc = 1.f / s;
        #pragma unroll
        for (int jn = 0; jn < 4; jn++){
            short4v pk;
            #pragma unroll
            for (int r = 0; r < 4; r++) pk[r] = f2bs(pr[jn][r] * rc);
            *(short4v*)&bufA[(16*wq + col)*LS + 16*jn + 4*qd] = pk;
        }
        short8 ap0 = *(const short8*)&bufA[(16*wq + col)*LS + 8*qd];
        short8 ap1 = *(const short8*)&bufA[(16*wq + col)*LS + 32 + 8*qd];
        short8 bv0 = *(const short8*)&bufV[(h*16 + col)*LS + 8*qd];
        short8 bv1 = *(const short8*)&bufV[(h*16 + col)*LS + 32 + 8*qd];
        float4v acc_o = zf;
        acc_o = MFMA(ap0, bv0, acc_o);
        acc_o = MFMA(ap1, bv1, acc_o);
        #pragma unroll
        for (int r = 0; r < 4; r++) yreg[h][r] = f2bs(acc_o[r]);
    }
    __syncthreads();        // all waves done with K cols / V rows
    #pragma unroll
    for (int h = 0; h < 4; h++){
        *(short4v*)&bufV[(h*16 + col)*LS + 16*wq + 4*qd] = yreg[h];   // Y^T
        #pragma unroll
        for (int r = 0; r < 4; r++)
            bufK[(16*wq + 4*qd + r)*LS + h*16 + col] = yreg[h][r];    // Y
    }
    __syncthreads();

    // ---- energy = Y Y^T (16x16, K=256) ----
    {
        float4v acc_e = zf;
        #pragma unroll
        for (int h = 0; h < 4; h++){
            short8 f0 = *(const short8*)&bufV[(h*16 + col)*LS + 8*qd];
            short8 f1 = *(const short8*)&bufV[(h*16 + col)*LS + 32 + 8*qd];
            acc_e = MFMA(f0, f0, acc_e);
            acc_e = MFMA(f1, f1, acc_e);
        }
        if (wq == 0){
            #pragma unroll
            for (int r = 0; r < 4; r++) energyS[(4*qd + r)*16 + col] = acc_e[r];
        }
    }
    __syncthreads();
    if (tid < 16){
        int i = tid; float m = -1e30f;
        for (int j = 0; j < 16; j++) m = fmaxf(m, energyS[i*16 + j]);
        float s = 0.f; float e[16];
        for (int j = 0; j < 16; j++){ e[j] = __expf(energyS[i*16 + j] - m); s += e[j]; }
        float rc = 1.f / s;
        for (int j = 0; j < 16; j++) soft_bf[i*32 + j] = f2bs(e[j] * rc);
        for (int j = 0; j < 16; j++) soft_bf[i*32 + 16 + j] = 0;
    }
    __syncthreads();

    // ---- lam + assemble XO -> bufK (overwrite Y slots, wave-private rows) ----
    {
        float gam = gammap[0];
        short8 asf = *(const short8*)&soft_bf[col*32 + 8*qd];
        #pragma unroll
        for (int h = 0; h < 4; h++){
            short8 ay = *(const short8*)&bufK[(16*wq + col)*LS + 16*h + (qd & 1)*8];
            float4v acc = MFMA(ay, asf, zf);
            short4v xv = xreg[h];
            #pragma unroll
            for (int r = 0; r < 4; r++){
                int ro = (16*wq + 4*qd + r)*LS + 16*h + col;
                float ot = bs2f(bufK[ro]);
                float qv = bs2f(bufQ[ro]);
                float xo = gam*acc[r] + ot + qv + bs2f(xv[r]);
                bufK[ro] = f2bs(xo);
            }
        }
    }
    __syncthreads();

    // ---- proj: C[c][t] -> XOf[t*66+c] packed f2 ----
    {
        short8 a0 = *(const short8*)&pwb[(16*wq + col)*64 + 8*qd];
        short8 a1 = *(const short8*)&pwb[(16*wq + col)*64 + 32 + 8*qd];
        float pbr[4];
        #pragma unroll
        for (int r = 0; r < 4; r++) pbr[r] = pb[16*wq + 4*qd + r];
        #pragma unroll
        for (int jn = 0; jn < 4; jn++){
            int t = 16*jn + col;
            short8 bx0 = *(const short8*)&bufK[t*LS + 8*qd];
            short8 bx1 = *(const short8*)&bufK[t*LS + 32 + 8*qd];
            float4v acc = zf;
            acc = MFMA(a0, bx0, acc);
            acc = MFMA(a1, bx1, acc);
            float2v w0 = {acc[0]+pbr[0], acc[1]+pbr[1]};
            float2v w1 = {acc[2]+pbr[2], acc[3]+pbr[3]};
            *(float2v*)&XOf[t*66 + 16*wq + 4*qd]     = w0;
            *(float2v*)&XOf[t*66 + 16*wq + 4*qd + 2] = w1;
        }
    }
    __syncthreads();

    // ================= fused channel-MLP =================
    {
        int p = tid & 63, qg = tid >> 6;
        float s = 0.f, ss = 0.f;
        #pragma unroll
        for (int j = 0; j < 8; j++){
            float2v v = *(const float2v*)&XOf[p*66 + qg*16 + 2*j];
            s += v[0]+v[1]; ss += v[0]*v[0] + v[1]*v[1];
        }
        sumS[qg*64 + p] = s; sqS[qg*64 + p] = ss;
    }
    __syncthreads();
    if (tid < 64){
        float s  = sumS[tid] + sumS[64+tid] + sumS[128+tid] + sumS[192+tid];
        float ss = sqS[tid]  + sqS[64+tid]  + sqS[128+tid]  + sqS[192+tid];
        float m = s * (1.f/64.f);
        float var = ss * (1.f/64.f) - m*m;
        muS[tid] = m; rinvS[tid] = rsqrtf(var + EPS);
    }
    __syncthreads();
    {
        int p = tid & 63, qg = tid >> 6;
        float m = muS[p], rv = rinvS[p];
        short8 o8[2];
        #pragma unroll
        for (int k = 0; k < 2; k++)
            #pragma unroll
            for (int j = 0; j < 8; j++){
                int c = qg*16 + k*8 + j;
                o8[k][j] = f2bs((XOf[p*66 + c] - m) * rv * n2g[c] + n2b[c]);
            }
        *(short8*)&tnb[p*LS + qg*16]     = o8[0];
        *(short8*)&tnb[p*LS + qg*16 + 8] = o8[1];
    }
    __syncthreads();
    // GEMM1: C[j][t]; h1b[t][j] packed
    {
        short8 a0 = *(const short8*)&f1b[(16*wq + col)*64 + 8*qd];
        short8 a1 = *(const short8*)&f1b[(16*wq + col)*64 + 32 + 8*qd];
        float fbr[4];
        #pragma unroll
        for (int r = 0; r < 4; r++) fbr[r] = fb1[16*wq + 4*qd + r];
        #pragma unroll
        for (int jn = 0; jn < 4; jn++){
            int t = 16*jn + col;
            short8 bx0 = *(const short8*)&tnb[t*LS + 8*qd];
            short8 bx1 = *(const short8*)&tnb[t*LS + 32 + 8*qd];
            float4v acc = zf;
            acc = MFMA(a0, bx0, acc);
            acc = MFMA(a1, bx1, acc);
            short4v pk;
            #pragma unroll
            for (int r = 0; r < 4; r++) pk[r] = f2bs(gelu_exact(acc[r] + fbr[r]));
            *(short4v*)&h1b[t*LS + 16*wq + 4*qd] = pk;
        }
    }
    __syncthreads();
    // GEMM2: out = xo + h1 @ W2^T + fb2 -> global planar fp32
    {
        short8 a0 = *(const short8*)&h1b[(16*wq + col)*LS + 8*qd];
        short8 a1 = *(const short8*)&h1b[(16*wq + col)*LS + 32 + 8*qd];
        #pragma unroll
        for (int jn = 0; jn < 4; jn++){
            int c2 = 16*jn + col;
            short8 f0 = *(const short8*)&f2b[c2*64 + 8*qd];
            short8 f1 = *(const short8*)&f2b[c2*64 + 32 + 8*qd];
            float4v acc = zf;
            acc = MFMA(a0, f0, acc);
            acc = MFMA(a1, f1, acc);
            float bv = fb2[c2];
            float4v ov;
            #pragma unroll
            for (int r = 0; r < 4; r++)
                ov[r] = acc[r] + bv + XOf[(16*wq + 4*qd + r)*66 + c2];
            int t0 = 16*wq + 4*qd;
            *(float4v*)(outp + base + (size_t)c2*HW + HWOF(t0)) = ov;
        }
    }
    #undef HWOF
}

extern "C" void kernel_launch(void* const* d_in, const int* in_sizes, int n_in,
                              void* d_out, int out_size, void* d_ws, size_t ws_size,
                              hipStream_t stream){
    const float* x        = (const float*)d_in[0];
    const float* l1_g1    = (const float*)d_in[1];
    const float* l1_b1    = (const float*)d_in[2];
    const float* l1_cw    = (const float*)d_in[3];
    const float* l1_cb    = (const float*)d_in[4];
    const float* l1_g2    = (const float*)d_in[5];
    const float* l1_b2    = (const float*)d_in[6];
    const float* l2_g1    = (const float*)d_in[7];
    const float* l2_b1    = (const float*)d_in[8];
    const float* l2_cw    = (const float*)d_in[9];
    const float* l2_cb    = (const float*)d_in[10];
    const float* l2_g2    = (const float*)d_in[11];
    const float* l2_b2    = (const float*)d_in[12];
    const float* pos1     = (const float*)d_in[13];
    const float* pos2     = (const float*)d_in[14];
    const float* q_w      = (const float*)d_in[15];
    const float* q_b      = (const float*)d_in[16];
    const float* kv_w     = (const float*)d_in[17];
    const float* kv_b     = (const float*)d_in[18];
    const float* rpb      = (const float*)d_in[19];
    const float* gamma    = (const float*)d_in[20];
    const float* proj_w   = (const float*)d_in[21];
    const float* proj_b   = (const float*)d_in[22];
    const float* norm2_g  = (const float*)d_in[23];
    const float* norm2_b  = (const float*)d_in[24];
    const float* fc1_w    = (const float*)d_in[25];
    const float* fc1_b    = (const float*)d_in[26];
    const float* fc2_w    = (const float*)d_in[27];
    const float* fc2_b    = (const float*)d_in[28];

    float* out = (float*)d_out;                 // final output only (written once)

    float* partS = (float*)d_ws;                // 2048*64 floats (512 KB)
    float* partQ = partS + (size_t)2048*64;     // 512 KB
    float* mu1   = partQ + (size_t)2048*64;     // 1024
    float* rinv1 = mu1 + 1024;                  // 1024
    float* mu2   = rinv1 + 1024;                // 2048
    float* rinv2 = mu2 + 2048;                  // 2048
    float* rowsumG = rinv2 + 2048;              // 128
    short* wbuf  = (short*)(rowsumG + 128);     // 32768 shorts

    k_pre  <<<1033, 256, 0, stream>>>(x, mu1, rinv1,
                                      l1_cw, l2_cw, q_w, kv_w, proj_w, fc1_w, fc2_w,
                                      wbuf, rowsumG);
    k_conv <<<1024, 256, 0, stream>>>(x, mu1, rinv1,
                                      l1_g1, l1_b1, l1_cb,
                                      l2_g1, l2_b1, l2_cb,
                                      wbuf, rowsumG,
                                      partS, partQ);
    k_fin  <<<512, 256, 0, stream>>>(partS, partQ, mu2, rinv2);
    k_attn <<<4096, 256, 0, stream>>>(x, out, mu1, rinv1, rowsumG,
                                      l1_cb, l2_cb,
                                      l1_g1, l1_b1, l2_g1, l2_b1,
                                      mu2, rinv2,
                                      l1_g2, l1_b2, l2_g2, l2_b2,
                                      pos1, pos2, wbuf, q_b, kv_b,
                                      rpb, gamma, proj_b,
                                      norm2_g, norm2_b, fc1_b, fc2_b);
}

// Round 8
// 333.975 us; speedup vs baseline: 1.0115x; 1.0004x over previous
//
#include <hip/hip_runtime.h>
#include <hip/hip_bf16.h>

typedef __hip_bfloat16 bf16;
typedef __attribute__((ext_vector_type(8))) short short8;
typedef __attribute__((ext_vector_type(4))) short short4v;
typedef __attribute__((ext_vector_type(4))) float float4v;
typedef __attribute__((ext_vector_type(2))) float float2v;

__device__ __forceinline__ short f2bs(float f){
    union { bf16 h; short s; } u; u.h = __float2bfloat16(f); return u.s;
}
__device__ __forceinline__ float bs2f(short s){
    return __uint_as_float(((unsigned)(unsigned short)s) << 16);
}
__device__ __forceinline__ float gelu_exact(float x){
    return 0.5f * x * (1.0f + erff(x * 0.70710678118654752440f));
}
#define MFMA(a,b,c) __builtin_amdgcn_mfma_f32_16x16x32_bf16((a),(b),(c),0,0,0)

#define HW 16384
#define NPLANE 1048576
#define EPS 1e-5f
#define LS 72             // LDS row stride in bf16 (144 B)

// wb layout (shorts): 0:w1b 4096:w2b 8192:qwb 12288:kvwb(8192) 20480:pwb 24576:fw1b 28672:fw2b
#define OFF_W1   0
#define OFF_W2   4096
#define OFF_QW   8192
#define OFF_KVW  12288
#define OFF_PW   20480
#define OFF_FW1  24576
#define OFF_FW2  28672

// ---------------- Kernel 1: LN1 stats (blocks 0..1023) + weight prep (1024..1032) ----------------
__global__ __launch_bounds__(256) void k_pre(const float* __restrict__ x,
                                             float* __restrict__ mu,
                                             float* __restrict__ rinv,
                                             const float* __restrict__ w1, const float* __restrict__ w2,
                                             const float* __restrict__ qw, const float* __restrict__ kvw,
                                             const float* __restrict__ pw, const float* __restrict__ fw1,
                                             const float* __restrict__ fw2,
                                             short* __restrict__ wb, float* __restrict__ rowsum){
    int bi = blockIdx.x;
    int tid = threadIdx.x;
    if (bi < 1024){
        const float* p = x + (size_t)bi * HW;
        float s = 0.f, ss = 0.f;
        for (int i = tid; i < HW/4; i += 256){
            float4v v = *(const float4v*)(p + i*4);
            #pragma unroll
            for (int k = 0; k < 4; k++){ s += v[k]; ss += v[k]*v[k]; }
        }
        __shared__ float rs[256], rss[256];
        rs[tid] = s; rss[tid] = ss; __syncthreads();
        for (int st = 128; st > 0; st >>= 1){
            if (tid < st){ rs[tid] += rs[tid+st]; rss[tid] += rss[tid+st]; }
            __syncthreads();
        }
        if (tid == 0){
            float m = rs[0] * (1.f/HW);
            float v = rss[0] * (1.f/HW) - m*m;
            mu[bi] = m; rinv[bi] = rsqrtf(v + EPS);
        }
    } else if (bi < 1032){
        int wi = bi - 1024;
        const float* src = wi==0?w1: wi==1?w2: wi==2?qw: wi==3?kvw: wi==4?(kvw+4096): wi==5?pw: wi==6?fw1: fw2;
        short* dst = wb + wi*4096;
        int base = tid*16;
        short8 o8[2];
        #pragma unroll
        for (int k = 0; k < 2; k++){
            float4v v0 = *(const float4v*)(src + base + 8*k);
            float4v v1 = *(const float4v*)(src + base + 8*k + 4);
            #pragma unroll
            for (int j = 0; j < 4; j++){ o8[k][j] = f2bs(v0[j]); o8[k][4+j] = f2bs(v1[j]); }
        }
        *(short8*)&dst[base]     = o8[0];
        *(short8*)&dst[base + 8] = o8[1];
    } else {
        if (tid < 128){
            int br = tid >> 6, o = tid & 63;
            const float* W = br ? w2 : w1;
            float s = 0.f;
            for (int c = 0; c < 64; c++) s += W[o*64 + c];
            rowsum[br*64 + o] = s;
        }
    }
}

// ---------------- Kernel 2: LN1 + conv stats, 4 tiles/block; ALSO spills xn packed ----------------
// xw[b][win][t][c] bf16 (33.5 MB): k_attn streams this contiguously instead of
// re-reading x channel-strided and redoing LN1.
__global__ __launch_bounds__(256, 4) void k_conv(const float* __restrict__ x,
                                              const float* __restrict__ mu,
                                              const float* __restrict__ rinv,
                                              const float* __restrict__ g1a, const float* __restrict__ b1a,
                                              const float* __restrict__ cb1,
                                              const float* __restrict__ g1b, const float* __restrict__ b1b,
                                              const float* __restrict__ cb2,
                                              const short* __restrict__ wb,
                                              const float* __restrict__ rowsum,
                                              short* __restrict__ xw,
                                              float* __restrict__ partS, float* __restrict__ partQ){
    int blk = blockIdx.x;
    int b = blk >> 6; int chunk = blk & 63;
    __shared__ __align__(16) short xn_bf[64*LS];
    const int tid = threadIdx.x;
    const int wq = tid >> 6, lane = tid & 63, qd = lane >> 4, col = lane & 15;
    const float4v zf = {0.f,0.f,0.f,0.f};
    const int p = tid & 63, cq = tid >> 6;

    float4v m4[4], r4[4];
    #pragma unroll
    for (int k = 0; k < 4; k++){
        m4[k] = *(const float4v*)(mu   + b*64 + 16*cq + 4*k);
        r4[k] = *(const float4v*)(rinv + b*64 + 16*cq + 4*k);
    }
    short8 a10 = *(const short8*)&wb[OFF_W1 + (16*wq + col)*64 + 8*qd];
    short8 a11 = *(const short8*)&wb[OFF_W1 + (16*wq + col)*64 + 32 + 8*qd];
    short8 a20 = *(const short8*)&wb[OFF_W2 + (16*wq + col)*64 + 8*qd];
    short8 a21 = *(const short8*)&wb[OFF_W2 + (16*wq + col)*64 + 32 + 8*qd];
    float cb1v[4], rs1v[4], cb2v[4], rs2v[4];
    #pragma unroll
    for (int r = 0; r < 4; r++){
        int o = 16*wq + 4*qd + r;
        cb1v[r] = cb1[o]; rs1v[r] = rowsum[o];
        cb2v[r] = cb2[o]; rs2v[r] = rowsum[64 + o];
    }
    float sa[2][4]  = {{0.f,0.f,0.f,0.f},{0.f,0.f,0.f,0.f}};
    float ssa[2][4] = {{0.f,0.f,0.f,0.f},{0.f,0.f,0.f,0.f}};

    for (int tl = 0; tl < 4; tl++){
        int hw0 = chunk*256 + tl*64;
        {
            const float* xb = x + (size_t)(b*64 + 16*cq)*HW + hw0 + p;
            short8 o8[2];
            #pragma unroll
            for (int k = 0; k < 2; k++)
                #pragma unroll
                for (int j = 0; j < 8; j++){
                    int jj = 8*k + j;
                    float v = xb[(size_t)jj*HW];
                    o8[k][j] = f2bs((v - m4[jj>>2][jj&3]) * r4[jj>>2][jj&3]);
                }
            *(short8*)&xn_bf[p*LS + 16*cq]     = o8[0];
            *(short8*)&xn_bf[p*LS + 16*cq + 8] = o8[1];
            // packed window-major spill for k_attn
            int hw = hw0 + p;
            int row = hw >> 7, cc = hw & 127;
            int win = (row >> 3)*16 + (cc >> 3);
            int t   = (row & 7)*8 + (cc & 7);
            short* dst = xw + ((((size_t)(b*256 + win)) << 6) + t)*64 + 16*cq;
            *(short8*)&dst[0] = o8[0];
            *(short8*)&dst[8] = o8[1];
        }
        __syncthreads();
        #pragma unroll
        for (int jn = 0; jn < 4; jn++){
            short8 bx0 = *(const short8*)&xn_bf[(16*jn + col)*LS + 8*qd];
            short8 bx1 = *(const short8*)&xn_bf[(16*jn + col)*LS + 32 + 8*qd];
            int hw = hw0 + 16*jn + col;
            {
                float4v acc = zf;
                acc = MFMA(a10, bx0, acc);
                acc = MFMA(a11, bx1, acc);
                float gl = g1a[hw], bl = b1a[hw];
                #pragma unroll
                for (int r = 0; r < 4; r++){
                    float v = gl*acc[r] + bl*rs1v[r] + cb1v[r];
                    sa[0][r] += v; ssa[0][r] += v*v;
                }
            }
            {
                float4v acc = zf;
                acc = MFMA(a20, bx0, acc);
                acc = MFMA(a21, bx1, acc);
                float gl = g1b[hw], bl = b1b[hw];
                #pragma unroll
                for (int r = 0; r < 4; r++){
                    float v = gl*acc[r] + bl*rs2v[r] + cb2v[r];
                    sa[1][r] += v; ssa[1][r] += v*v;
                }
            }
        }
        __syncthreads();
    }

    #pragma unroll
    for (int br = 0; br < 2; br++)
        #pragma unroll
        for (int r = 0; r < 4; r++){
            float s = sa[br][r], ss = ssa[br][r];
            s += __shfl_xor(s, 1); ss += __shfl_xor(ss, 1);
            s += __shfl_xor(s, 2); ss += __shfl_xor(ss, 2);
            s += __shfl_xor(s, 4); ss += __shfl_xor(ss, 4);
            s += __shfl_xor(s, 8); ss += __shfl_xor(ss, 8);
            if (col == 0){
                int o = 16*wq + 4*qd + r;
                size_t pi = ((size_t)(br*16 + b)*64 + o)*64 + chunk;
                partS[pi] = s; partQ[pi] = ss;
            }
        }
}

// ---------------- Kernel 3: reduce LN2 partials (2048 rows x 64 chunks), wave-per-row ----------------
__global__ __launch_bounds__(256) void k_fin(const float* __restrict__ partS,
                                             const float* __restrict__ partQ,
                                             float* __restrict__ mu2,
                                             float* __restrict__ rinv2){
    int row = blockIdx.x*4 + (threadIdx.x >> 6);   // 0..2047
    int lane = threadIdx.x & 63;
    float s  = partS[(size_t)row*64 + lane];
    float ss = partQ[(size_t)row*64 + lane];
    #pragma unroll
    for (int st = 1; st < 64; st <<= 1){
        s  += __shfl_xor(s,  st);
        ss += __shfl_xor(ss, st);
    }
    if (lane == 0){
        float m = s * (1.f/HW);
        float v = ss * (1.f/HW) - m*m;
        mu2[row] = m; rinv2[row] = rsqrtf(v + EPS);
    }
}

// ---------------- Kernel 4: full fused window pipeline (round-4 structure, packed xn input) --------
__global__ __launch_bounds__(256, 4) void k_attn(const short* __restrict__ xw, float* __restrict__ outp,
                                              const float* __restrict__ rowsum,
                                              const float* __restrict__ cb1, const float* __restrict__ cb2,
                                              const float* __restrict__ g1a, const float* __restrict__ b1a,
                                              const float* __restrict__ g1b, const float* __restrict__ b1b,
                                              const float* __restrict__ mu2, const float* __restrict__ rinv2,
                                              const float* __restrict__ g2a, const float* __restrict__ b2a,
                                              const float* __restrict__ g2b, const float* __restrict__ b2b,
                                              const float* __restrict__ pos1, const float* __restrict__ pos2,
                                              const short* __restrict__ wb,
                                              const float* __restrict__ qb, const float* __restrict__ kvb,
                                              const float* __restrict__ rpb, const float* __restrict__ gammap,
                                              const float* __restrict__ pb,
                                              const float* __restrict__ n2g, const float* __restrict__ n2b,
                                              const float* __restrict__ fb1,
                                              const float* __restrict__ fb2){
    int B = blockIdx.x;
    int hy = (B & 7) | ((B >> 5) & 8);
    int wx = (((B >> 9) & 7) << 1) | ((B >> 3) & 1);
    int b  = (B >> 4) & 15;
    int win = hy*16 + wx;

    const short* qwb  = wb + OFF_QW;
    const short* kvwb = wb + OFF_KVW;
    const short* pwb  = wb + OFF_PW;
    const short* f1b  = wb + OFF_FW1;
    const short* f2b  = wb + OFF_FW2;

    __shared__ __align__(16) char smem[40464];
    short* bufA = (short*)smem;                    // X1w -> P (wave-private)
    short* bufK = (short*)(smem + 9216);           // K -> Y[t][c] -> XO[t][c]
    short* bufV = (short*)(smem + 18432);          // xn -> V^T[c][t] -> Y^T[c][t]
    short* bufQ = (short*)(smem + 27648);          // X2w -> Q[t][c]
    float* rpb_lds = (float*)(smem + 36864);       // 3600 (dead after head loop)
    float* energyS = (float*)(smem + 36864);       // 1024, aliases rpb
    short* soft_bf = (short*)(smem + 37888);       // 1024, aliases rpb
    // tail aliases:
    float* XOf  = (float*)(smem + 18432);          // 64x66 fp32 (16896 B) over bufV+bufQ
    short* tnb  = (short*)smem;                    // tn bf16 over bufA
    short* h1b  = (short*)(smem + 9216);           // h1 over bufK
    float* sumS = (float*)(smem + 36864);          // 1024
    float* sqS  = (float*)(smem + 37888);          // 1024
    float* muS  = (float*)(smem + 38912);          // 256
    float* rinvS= (float*)(smem + 39168);          // 256

    const int tid = threadIdx.x;
    const int wq = tid >> 6, lane = tid & 63, qd = lane >> 4, col = lane & 15;
    size_t base = (size_t)b * NPLANE;
    #define HWOF(t) ((hy*8 + ((t)>>3))*128 + wx*8 + ((t)&7))

    const float4v zf = {0.f,0.f,0.f,0.f};
    const short8 zero8 = {0,0,0,0,0,0,0,0};

    for (int i = tid; i < 900; i += 256) rpb_lds[i] = rpb[i];

    // ---- P0: stream packed xn window (fully contiguous) -> bufV ----
    {
        int t = tid >> 2, c0 = (tid & 3) << 4;
        const short* src = xw + (((size_t)(b*256 + win)) << 12) + t*64 + c0;
        short8 v0 = *(const short8*)src;
        short8 v1 = *(const short8*)(src + 8);
        *(short8*)&bufV[t*LS + c0]     = v0;
        *(short8*)&bufV[t*LS + c0 + 8] = v1;
    }
    __syncthreads();

    // ---- P1: both convs from xn, fused LN1-affine + LN2 + GELU + pos epilogue ----
    {
        short8 a10 = *(const short8*)&wb[OFF_W1 + (16*wq + col)*64 + 8*qd];
        short8 a11 = *(const short8*)&wb[OFF_W1 + (16*wq + col)*64 + 32 + 8*qd];
        short8 a20 = *(const short8*)&wb[OFF_W2 + (16*wq + col)*64 + 8*qd];
        short8 a21 = *(const short8*)&wb[OFF_W2 + (16*wq + col)*64 + 32 + 8*qd];
        float cb1v[4], rs1v[4], m2a[4], rv2a[4];
        float cb2v[4], rs2v[4], m2b[4], rv2b[4];
        #pragma unroll
        for (int r = 0; r < 4; r++){
            int o = 16*wq + 4*qd + r;
            cb1v[r] = cb1[o]; rs1v[r] = rowsum[o];
            m2a[r] = mu2[b*64 + o]; rv2a[r] = rinv2[b*64 + o];
            cb2v[r] = cb2[o]; rs2v[r] = rowsum[64 + o];
            m2b[r] = mu2[1024 + b*64 + o]; rv2b[r] = rinv2[1024 + b*64 + o];
        }
        #pragma unroll
        for (int jn = 0; jn < 4; jn++){
            int t = 16*jn + col; int hw = HWOF(t);
            short8 bx0 = *(const short8*)&bufV[t*LS + 8*qd];
            short8 bx1 = *(const short8*)&bufV[t*LS + 32 + 8*qd];
            {
                float4v acc = zf;
                acc = MFMA(a10, bx0, acc);
                acc = MFMA(a11, bx1, acc);
                float gl = g1a[hw], bl = b1a[hw], gg = g2a[hw], bo = b2a[hw];
                float4v p4 = *(const float4v*)(pos1 + t*64 + 16*wq + 4*qd);
                short4v pk;
                #pragma unroll
                for (int r = 0; r < 4; r++){
                    float v = gl*acc[r] + bl*rs1v[r] + cb1v[r];
                    float z = (v - m2a[r]) * rv2a[r] * gg + bo;
                    pk[r] = f2bs(gelu_exact(z) + p4[r]);
                }
                *(short4v*)&bufA[t*LS + 16*wq + 4*qd] = pk;
            }
            {
                float4v acc = zf;
                acc = MFMA(a20, bx0, acc);
                acc = MFMA(a21, bx1, acc);
                float gl = g1b[hw], bl = b1b[hw], gg = g2b[hw], bo = b2b[hw];
                float4v p4 = *(const float4v*)(pos2 + t*64 + 16*wq + 4*qd);
                short4v pk;
                #pragma unroll
                for (int r = 0; r < 4; r++){
                    float v = gl*acc[r] + bl*rs2v[r] + cb2v[r];
                    float z = (v - m2b[r]) * rv2b[r] * gg + bo;
                    pk[r] = f2bs(gelu_exact(z) + p4[r]);
                }
                *(short4v*)&bufQ[t*LS + 16*wq + 4*qd] = pk;
            }
        }
    }
    __syncthreads();

    // ---- P2: V^T and K from X2w (bufQ); xn (bufV) dead -> V^T target ----
    {
        short8 ax0 = *(const short8*)&bufQ[(16*wq + col)*LS + 8*qd];
        short8 ax1 = *(const short8*)&bufQ[(16*wq + col)*LS + 32 + 8*qd];
        #pragma unroll
        for (int jn = 0; jn < 4; jn++){
            int c = 16*jn + col;
            short8 wv0 = *(const short8*)&kvwb[(64 + c)*64 + 8*qd];
            short8 wv1 = *(const short8*)&kvwb[(64 + c)*64 + 32 + 8*qd];
            float4v acc = zf;
            acc = MFMA(ax0, wv0, acc);
            acc = MFMA(ax1, wv1, acc);
            float bv = kvb[64 + c];
            short4v pk;
            #pragma unroll
            for (int r = 0; r < 4; r++) pk[r] = f2bs(acc[r] + bv);
            *(short4v*)&bufV[c*LS + 16*wq + 4*qd] = pk;
        }
        short8 a0 = *(const short8*)&kvwb[(16*wq + col)*64 + 8*qd];
        short8 a1 = *(const short8*)&kvwb[(16*wq + col)*64 + 32 + 8*qd];
        float kbr[4];
        #pragma unroll
        for (int r = 0; r < 4; r++) kbr[r] = kvb[16*wq + 4*qd + r];
        #pragma unroll
        for (int jn = 0; jn < 4; jn++){
            int t = 16*jn + col;
            short8 bx0 = *(const short8*)&bufQ[t*LS + 8*qd];
            short8 bx1 = *(const short8*)&bufQ[t*LS + 32 + 8*qd];
            float4v acc = zf;
            acc = MFMA(a0, bx0, acc);
            acc = MFMA(a1, bx1, acc);
            short4v pk;
            #pragma unroll
            for (int r = 0; r < 4; r++) pk[r] = f2bs(acc[r] + kbr[r]);
            *(short4v*)&bufK[t*LS + 16*wq + 4*qd] = pk;
        }
    }
    __syncthreads();

    // ---- P3: Q from X1w (bufA) -> bufQ (X2w dead); capture X1w residual ----
    {
        short8 a0 = *(const short8*)&qwb[(16*wq + col)*64 + 8*qd];
        short8 a1 = *(const short8*)&qwb[(16*wq + col)*64 + 32 + 8*qd];
        float qbr[4];
        #pragma unroll
        for (int r = 0; r < 4; r++) qbr[r] = qb[16*wq + 4*qd + r];
        #pragma unroll
        for (int jn = 0; jn < 4; jn++){
            int t = 16*jn + col;
            short8 bx0 = *(const short8*)&bufA[t*LS + 8*qd];
            short8 bx1 = *(const short8*)&bufA[t*LS + 32 + 8*qd];
            float4v acc = zf;
            acc = MFMA(a0, bx0, acc);
            acc = MFMA(a1, bx1, acc);
            short4v pk;
            #pragma unroll
            for (int r = 0; r < 4; r++) pk[r] = f2bs((acc[r] + qbr[r]) * 0.25f);
            *(short4v*)&bufQ[t*LS + 16*wq + 4*qd] = pk;
        }
    }
    short4v xreg[4];
    #pragma unroll
    for (int h = 0; h < 4; h++){
        short4v xr;
        #pragma unroll
        for (int r = 0; r < 4; r++)
            xr[r] = bufA[(16*wq + 4*qd + r)*LS + 16*h + col];
        xreg[h] = xr;
    }
    __syncthreads();

    int idx_t[4][4];
    {
        int t = 16*wq + col, ty = t >> 3, tx = t & 7;
        #pragma unroll
        for (int jn = 0; jn < 4; jn++)
            #pragma unroll
            for (int r = 0; r < 4; r++){
                int u = 16*jn + 4*qd + r;
                idx_t[jn][r] = (ty - (u>>3) + 7)*15 + (tx - (u&7) + 7);
            }
    }

    // ---- head loop (round-4 structure: one barrier per head) ----
    for (int h = 0; h < 4; h++){
        short8 bq = *(const short8*)&bufQ[(16*wq + col)*LS + h*16 + (qd & 1)*8];
        float pr[4][4];
        #pragma unroll
        for (int jn = 0; jn < 4; jn++){
            short8 ak = *(const short8*)&bufK[(16*jn + col)*LS + h*16 + (qd & 1)*8];
            if (qd >= 2) ak = zero8;
            float4v acc = MFMA(ak, bq, zf);
            #pragma unroll
            for (int r = 0; r < 4; r++)
                pr[jn][r] = acc[r] + rpb_lds[idx_t[jn][r]*4 + h];
        }
        float m = pr[0][0];
        #pragma unroll
        for (int jn = 0; jn < 4; jn++)
            #pragma unroll
            for (int r = 0; r < 4; r++) m = fmaxf(m, pr[jn][r]);
        m = fmaxf(m, __shfl_xor(m, 16));
        m = fmaxf(m, __shfl_xor(m, 32));
        float s = 0.f;
        #pragma unroll
        for (int jn = 0; jn < 4; jn++)
            #pragma unroll
            for (int r = 0; r < 4; r++){ pr[jn][r] = __expf(pr[jn][r] - m); s += pr[jn][r]; }
        s += __shfl_xor(s, 16);
        s += __shfl_xor(s, 32);
        float rc = 1.f / s;
        #pragma unroll
        for (int jn = 0; jn < 4; jn++){
            short4v pk;
            #pragma unroll
            for (int r = 0; r < 4; r++) pk[r] = f2bs(pr[jn][r] * rc);
            *(short4v*)&bufA[(16*wq + col)*LS + 16*jn + 4*qd] = pk;
        }
        short8 ap0 = *(const short8*)&bufA[(16*wq + col)*LS + 8*qd];
        short8 ap1 = *(const short8*)&bufA[(16*wq + col)*LS + 32 + 8*qd];
        short8 bv0 = *(const short8*)&bufV[(h*16 + col)*LS + 8*qd];
        short8 bv1 = *(const short8*)&bufV[(h*16 + col)*LS + 32 + 8*qd];
        float4v acc_o = zf;
        acc_o = MFMA(ap0, bv0, acc_o);
        acc_o = MFMA(ap1, bv1, acc_o);
        __syncthreads();          // all waves done reading V rows of this head
        short4v ot;
        #pragma unroll
        for (int r = 0; r < 4; r++) ot[r] = f2bs(acc_o[r]);
        *(short4v*)&bufV[(h*16 + col)*LS + 16*wq + 4*qd] = ot;   // Y^T
        #pragma unroll
        for (int r = 0; r < 4; r++)
            bufK[(16*wq + 4*qd + r)*LS + h*16 + col] = ot[r];    // Y
    }
    __syncthreads();

    // ---- energy = Y Y^T (16x16, K=256) ----
    {
        float4v acc_e = zf;
        #pragma unroll
        for (int h = 0; h < 4; h++){
            short8 f0 = *(const short8*)&bufV[(h*16 + col)*LS + 8*qd];
            short8 f1 = *(const short8*)&bufV[(h*16 + col)*LS + 32 + 8*qd];
            acc_e = MFMA(f0, f0, acc_e);
            acc_e = MFMA(f1, f1, acc_e);
        }
        if (wq == 0){
            #pragma unroll
            for (int r = 0; r < 4; r++) energyS[(4*qd + r)*16 + col] = acc_e[r];
        }
    }
    __syncthreads();
    if (tid < 16){
        int i = tid; float m = -1e30f;
        for (int j = 0; j < 16; j++) m = fmaxf(m, energyS[i*16 + j]);
        float s = 0.f; float e[16];
        for (int j = 0; j < 16; j++){ e[j] = __expf(energyS[i*16 + j] - m); s += e[j]; }
        float rc = 1.f / s;
        for (int j = 0; j < 16; j++) soft_bf[i*32 + j] = f2bs(e[j] * rc);
        for (int j = 0; j < 16; j++) soft_bf[i*32 + 16 + j] = 0;
    }
    __syncthreads();

    // ---- lam + assemble XO -> bufK (overwrite Y slots, wave-private rows) ----
    {
        float gam = gammap[0];
        short8 asf = *(const short8*)&soft_bf[col*32 + 8*qd];
        #pragma unroll
        for (int h = 0; h < 4; h++){
            short8 ay = *(const short8*)&bufK[(16*wq + col)*LS + 16*h + (qd & 1)*8];
            float4v acc = MFMA(ay, asf, zf);
            short4v xv = xreg[h];
            #pragma unroll
            for (int r = 0; r < 4; r++){
                int ro = (16*wq + 4*qd + r)*LS + 16*h + col;
                float ot = bs2f(bufK[ro]);
                float qv = bs2f(bufQ[ro]);
                float xo = gam*acc[r] + ot + qv + bs2f(xv[r]);
                bufK[ro] = f2bs(xo);
            }
        }
    }
    __syncthreads();

    // ---- proj: C[c][t] -> XOf[t*66+c] packed f2 ----
    {
        short8 a0 = *(const short8*)&pwb[(16*wq + col)*64 + 8*qd];
        short8 a1 = *(const short8*)&pwb[(16*wq + col)*64 + 32 + 8*qd];
        float pbr[4];
        #pragma unroll
        for (int r = 0; r < 4; r++) pbr[r] = pb[16*wq + 4*qd + r];
        #pragma unroll
        for (int jn = 0; jn < 4; jn++){
            int t = 16*jn + col;
            short8 bx0 = *(const short8*)&bufK[t*LS + 8*qd];
            short8 bx1 = *(const short8*)&bufK[t*LS + 32 + 8*qd];
            float4v acc = zf;
            acc = MFMA(a0, bx0, acc);
            acc = MFMA(a1, bx1, acc);
            float2v w0 = {acc[0]+pbr[0], acc[1]+pbr[1]};
            float2v w1 = {acc[2]+pbr[2], acc[3]+pbr[3]};
            *(float2v*)&XOf[t*66 + 16*wq + 4*qd]     = w0;
            *(float2v*)&XOf[t*66 + 16*wq + 4*qd + 2] = w1;
        }
    }
    __syncthreads();

    // ================= fused channel-MLP =================
    {
        int p = tid & 63, qg = tid >> 6;
        float s = 0.f, ss = 0.f;
        #pragma unroll
        for (int j = 0; j < 8; j++){
            float2v v = *(const float2v*)&XOf[p*66 + qg*16 + 2*j];
            s += v[0]+v[1]; ss += v[0]*v[0] + v[1]*v[1];
        }
        sumS[qg*64 + p] = s; sqS[qg*64 + p] = ss;
    }
    __syncthreads();
    if (tid < 64){
        float s  = sumS[tid] + sumS[64+tid] + sumS[128+tid] + sumS[192+tid];
        float ss = sqS[tid]  + sqS[64+tid]  + sqS[128+tid]  + sqS[192+tid];
        float m = s * (1.f/64.f);
        float var = ss * (1.f/64.f) - m*m;
        muS[tid] = m; rinvS[tid] = rsqrtf(var + EPS);
    }
    __syncthreads();
    {
        int p = tid & 63, qg = tid >> 6;
        float m = muS[p], rv = rinvS[p];
        short8 o8[2];
        #pragma unroll
        for (int k = 0; k < 2; k++)
            #pragma unroll
            for (int j = 0; j < 8; j++){
                int c = qg*16 + k*8 + j;
                o8[k][j] = f2bs((XOf[p*66 + c] - m) * rv * n2g[c] + n2b[c]);
            }
        *(short8*)&tnb[p*LS + qg*16]     = o8[0];
        *(short8*)&tnb[p*LS + qg*16 + 8] = o8[1];
    }
    __syncthreads();
    // GEMM1: C[j][t]; h1b[t][j] packed
    {
        short8 a0 = *(const short8*)&f1b[(16*wq + col)*64 + 8*qd];
        short8 a1 = *(const short8*)&f1b[(16*wq + col)*64 + 32 + 8*qd];
        float fbr[4];
        #pragma unroll
        for (int r = 0; r < 4; r++) fbr[r] = fb1[16*wq + 4*qd + r];
        #pragma unroll
        for (int jn = 0; jn < 4; jn++){
            int t = 16*jn + col;
            short8 bx0 = *(const short8*)&tnb[t*LS + 8*qd];
            short8 bx1 = *(const short8*)&tnb[t*LS + 32 + 8*qd];
            float4v acc = zf;
            acc = MFMA(a0, bx0, acc);
            acc = MFMA(a1, bx1, acc);
            short4v pk;
            #pragma unroll
            for (int r = 0; r < 4; r++) pk[r] = f2bs(gelu_exact(acc[r] + fbr[r]));
            *(short4v*)&h1b[t*LS + 16*wq + 4*qd] = pk;
        }
    }
    __syncthreads();
    // GEMM2: out = xo + h1 @ W2^T + fb2 -> global planar fp32
    {
        short8 a0 = *(const short8*)&h1b[(16*wq + col)*LS + 8*qd];
        short8 a1 = *(const short8*)&h1b[(16*wq + col)*LS + 32 + 8*qd];
        #pragma unroll
        for (int jn = 0; jn < 4; jn++){
            int c2 = 16*jn + col;
            short8 f0 = *(const short8*)&f2b[c2*64 + 8*qd];
            short8 f1 = *(const short8*)&f2b[c2*64 + 32 + 8*qd];
            float4v acc = zf;
            acc = MFMA(a0, f0, acc);
            acc = MFMA(a1, f1, acc);
            float bv = fb2[c2];
            float4v ov;
            #pragma unroll
            for (int r = 0; r < 4; r++)
                ov[r] = acc[r] + bv + XOf[(16*wq + 4*qd + r)*66 + c2];
            int t0 = 16*wq + 4*qd;
            *(float4v*)(outp + base + (size_t)c2*HW + HWOF(t0)) = ov;
        }
    }
    #undef HWOF
}

extern "C" void kernel_launch(void* const* d_in, const int* in_sizes, int n_in,
                              void* d_out, int out_size, void* d_ws, size_t ws_size,
                              hipStream_t stream){
    const float* x        = (const float*)d_in[0];
    const float* l1_g1    = (const float*)d_in[1];
    const float* l1_b1    = (const float*)d_in[2];
    const float* l1_cw    = (const float*)d_in[3];
    const float* l1_cb    = (const float*)d_in[4];
    const float* l1_g2    = (const float*)d_in[5];
    const float* l1_b2    = (const float*)d_in[6];
    const float* l2_g1    = (const float*)d_in[7];
    const float* l2_b1    = (const float*)d_in[8];
    const float* l2_cw    = (const float*)d_in[9];
    const float* l2_cb    = (const float*)d_in[10];
    const float* l2_g2    = (const float*)d_in[11];
    const float* l2_b2    = (const float*)d_in[12];
    const float* pos1     = (const float*)d_in[13];
    const float* pos2     = (const float*)d_in[14];
    const float* q_w      = (const float*)d_in[15];
    const float* q_b      = (const float*)d_in[16];
    const float* kv_w     = (const float*)d_in[17];
    const float* kv_b     = (const float*)d_in[18];
    const float* rpb      = (const float*)d_in[19];
    const float* gamma    = (const float*)d_in[20];
    const float* proj_w   = (const float*)d_in[21];
    const float* proj_b   = (const float*)d_in[22];
    const float* norm2_g  = (const float*)d_in[23];
    const float* norm2_b  = (const float*)d_in[24];
    const float* fc1_w    = (const float*)d_in[25];
    const float* fc1_b    = (const float*)d_in[26];
    const float* fc2_w    = (const float*)d_in[27];
    const float* fc2_b    = (const float*)d_in[28];

    float* out = (float*)d_out;                 // final output only (written once)

    short* xw    = (short*)d_ws;                // 16*256*64*64 shorts (33.5 MB) packed xn
    float* partS = (float*)(xw + (size_t)16*256*4096);  // 512 KB
    float* partQ = partS + (size_t)2048*64;     // 512 KB
    float* mu1   = partQ + (size_t)2048*64;     // 1024
    float* rinv1 = mu1 + 1024;                  // 1024
    float* mu2   = rinv1 + 1024;                // 2048
    float* rinv2 = mu2 + 2048;                  // 2048
    float* rowsumG = rinv2 + 2048;              // 128
    short* wbuf  = (short*)(rowsumG + 128);     // 32768 shorts

    k_pre  <<<1033, 256, 0, stream>>>(x, mu1, rinv1,
                                      l1_cw, l2_cw, q_w, kv_w, proj_w, fc1_w, fc2_w,
                                      wbuf, rowsumG);
    k_conv <<<1024, 256, 0, stream>>>(x, mu1, rinv1,
                                      l1_g1, l1_b1, l1_cb,
                                      l2_g1, l2_b1, l2_cb,
                                      wbuf, rowsumG, xw,
                                      partS, partQ);
    k_fin  <<<512, 256, 0, stream>>>(partS, partQ, mu2, rinv2);
    k_attn <<<4096, 256, 0, stream>>>(xw, out, rowsumG,
                                      l1_cb, l2_cb,
                                      l1_g1, l1_b1, l2_g1, l2_b1,
                                      mu2, rinv2,
                                      l1_g2, l1_b2, l2_g2, l2_b2,
                                      pos1, pos2, wbuf, q_b, kv_b,
                                      rpb, gamma, proj_b,
                                      norm2_g, norm2_b, fc1_b, fc2_b);
}